// Round 6
// baseline (493.538 us; speedup 1.0000x reference)
//
#include <hip/hip_runtime.h>
#include <hip/hip_bf16.h>
#include <math.h>

#define H 768
#define BM 128

typedef __attribute__((ext_vector_type(4))) float f32x4;
typedef __attribute__((ext_vector_type(8))) short bf16x8;

__device__ __forceinline__ float bf2f(unsigned u16v){
  return __uint_as_float((u16v & 0xffffu) << 16);
}
__device__ __forceinline__ unsigned f2bf2(float a, float b){
  __hip_bfloat16 ha = __float2bfloat16(a), hb = __float2bfloat16(b);
  return (unsigned)*(unsigned short*)&ha | ((unsigned)*(unsigned short*)&hb << 16);
}
__device__ __forceinline__ float gelu_exact(float x){
  return 0.5f * x * (1.0f + erff(x * 0.70710678118654752f));
}
__device__ __forceinline__ void gload16(const void* g, void* l){
  __builtin_amdgcn_global_load_lds(
      (const __attribute__((address_space(1))) unsigned int*)g,
      (__attribute__((address_space(3))) unsigned int*)l,
      16, 0, 0);
}
__device__ __forceinline__ float wave_sum(float p){
#pragma unroll
  for (int o = 32; o; o >>= 1) p += __shfl_xor(p, o);
  return p;
}

// ---------------- LayerNorm + exact GELU: one WAVE per row, f32 in, bf16 out ----------------
__global__ __launch_bounds__(256) void lnw_kernel(
    const float* __restrict__ in, const float* __restrict__ g,
    const float* __restrict__ b, __hip_bfloat16* __restrict__ out, int rows){
  int row = blockIdx.x * 4 + (threadIdx.x >> 6);
  if (row >= rows) return;
  int lane = threadIdx.x & 63;
  const float* rp = in + (size_t)row * H;
  float v[12];
#pragma unroll
  for (int i = 0; i < 3; i++){
    float4 t = *(const float4*)&rp[(lane + i * 64) * 4];
    v[i*4+0] = t.x; v[i*4+1] = t.y; v[i*4+2] = t.z; v[i*4+3] = t.w;
  }
  float s = 0.f;
#pragma unroll
  for (int t = 0; t < 12; t++) s += v[t];
  float mean = wave_sum(s) * (1.0f / H);
  float s2 = 0.f;
#pragma unroll
  for (int t = 0; t < 12; t++){ float d = v[t] - mean; s2 += d * d; }
  float rstd = rsqrtf(wave_sum(s2) * (1.0f / H) + 1e-5f);
  unsigned* op = (unsigned*)(out + (size_t)row * H);
#pragma unroll
  for (int i = 0; i < 3; i++){
    float4 gv = *(const float4*)&g[(lane + i * 64) * 4];
    float4 bv = *(const float4*)&b[(lane + i * 64) * 4];
    float z0 = gelu_exact((v[i*4+0] - mean) * rstd * gv.x + bv.x);
    float z1 = gelu_exact((v[i*4+1] - mean) * rstd * gv.y + bv.y);
    float z2 = gelu_exact((v[i*4+2] - mean) * rstd * gv.z + bv.z);
    float z3 = gelu_exact((v[i*4+3] - mean) * rstd * gv.w + bv.w);
    uint2 pk; pk.x = f2bf2(z0, z1); pk.y = f2bf2(z2, z3);
    *(uint2*)&op[lane * 2 + i * 128] = pk;
  }
}

// ---------------- weight transpose + f32->bf16: WT[n][k] = W[k][n] ----------------
__global__ __launch_bounds__(256) void wt_bf16_kernel(
    const float* __restrict__ W, __hip_bfloat16* __restrict__ WT){
  __shared__ float tile[32][33];
  int k0 = blockIdx.x * 32, n0 = blockIdx.y * 32;
  int tx = threadIdx.x & 31, ty = threadIdx.x >> 5;   // 32 x 8
#pragma unroll
  for (int i = 0; i < 32; i += 8)
    tile[ty + i][tx] = W[(size_t)(k0 + ty + i) * H + n0 + tx];
  __syncthreads();
#pragma unroll
  for (int i = 0; i < 32; i += 8)
    WT[(size_t)(n0 + ty + i) * H + k0 + tx] = __float2bfloat16(tile[tx][ty + i]);
}

// ---------------- fused bf16 MFMA GEMM, optional row-compaction indirection ----------------
// [Cl | Cr] = A[*,768] @ WT[1536,768]^T (+bias).
// xl blocks: rows are rmap[row] for row < *nr_p (compacted); identity if rmap==null.
// xr blocks: original rows < Mr.
__global__ __launch_bounds__(256, 3) void gemm_fused_kernel(
    const __hip_bfloat16* __restrict__ A,
    const __hip_bfloat16* __restrict__ WT,
    const float* __restrict__ bl, const float* __restrict__ br,
    __hip_bfloat16* __restrict__ Cl, __hip_bfloat16* __restrict__ Cr,
    const int* __restrict__ rmap, const int* __restrict__ nr_p,
    int panels, int Mr){
  __shared__ char smem[49152];          // 3 x (As 8KB | Bs 8KB)

  int wgid = blockIdx.x;
  int xcd = wgid & 7, j = wgid >> 3;
  int panel = xcd * (panels >> 3) + j / 12;
  int colblk = j % 12;
  int row0 = panel * BM;
  const bool is_r = colblk >= 6;
  int nrl = panels * BM;
  if (rmap && nr_p) nrl = *nr_p;                       // device-side compacted count
  if (is_r){ if (row0 >= Mr) return; }
  else     { if (row0 >= nrl) return; }
  const bool remap = (rmap != nullptr) && !is_r;

  const int t = threadIdx.x;
  const int sr = t >> 2;                               // staging row 0..63
  const int scs = (((t & 3) ^ ((sr >> 1) & 3)) * 8);   // pre-swizzled global col
  const int t16 = t * 16;                              // linear LDS byte slot
  int ra0 = row0 + sr, ra1 = row0 + sr + 64;
  if (remap){
    ra0 = rmap[min(ra0, nrl - 1)];
    ra1 = rmap[min(ra1, nrl - 1)];
  }
  const __hip_bfloat16* pa0 = A + (size_t)ra0 * H + scs;
  const __hip_bfloat16* pa1 = A + (size_t)ra1 * H + scs;
  const __hip_bfloat16* pb0 = WT + (size_t)(colblk * 128 + sr) * H + scs;
  const __hip_bfloat16* pb1 = pb0 + (size_t)64 * H;

  const int l = t & 63, w = t >> 6;
  const int wm = (w >> 1) * 64, wn = (w & 1) * 64;
  const int r0 = l & 15;
  const int kcs2 = (((l >> 4) ^ ((r0 >> 1) & 3)) * 16); // swizzled frag byte col

  f32x4 acc[4][4];
#pragma unroll
  for (int m = 0; m < 4; m++)
#pragma unroll
    for (int n = 0; n < 4; n++) acc[m][n] = (f32x4){0.f, 0.f, 0.f, 0.f};

#define STAGE(kt, b) do{                                   \
    int _k0 = (kt) * 32;                                   \
    char* _bs = smem + (b) * 16384;                        \
    gload16(pa0 + _k0, _bs + t16);                         \
    gload16(pa1 + _k0, _bs + 4096 + t16);                  \
    gload16(pb0 + _k0, _bs + 8192 + t16);                  \
    gload16(pb1 + _k0, _bs + 12288 + t16);                 \
  }while(0)

  STAGE(0, 0);
  STAGE(1, 1);

  for (int kt = 0; kt < 24; kt++){
    if (kt < 23) asm volatile("s_waitcnt vmcnt(4)" ::: "memory");
    else         asm volatile("s_waitcnt vmcnt(0)" ::: "memory");
    __builtin_amdgcn_s_barrier();
    __builtin_amdgcn_sched_barrier(0);
    if (kt + 2 < 24) STAGE(kt + 2, (kt + 2) % 3);
    const char* base = smem + (kt % 3) * 16384;
    bf16x8 af[4], bfr[4];
#pragma unroll
    for (int m = 0; m < 4; m++)
      af[m]  = *(const bf16x8*)(base + (wm + m * 16 + r0) * 64 + kcs2);
#pragma unroll
    for (int n = 0; n < 4; n++)
      bfr[n] = *(const bf16x8*)(base + 8192 + (wn + n * 16 + r0) * 64 + kcs2);
#pragma unroll
    for (int m = 0; m < 4; m++)
#pragma unroll
      for (int n = 0; n < 4; n++)
        acc[m][n] = __builtin_amdgcn_mfma_f32_16x16x32_bf16(af[m], bfr[n], acc[m][n], 0, 0, 0);
  }
#undef STAGE

  // epilogue: stage C tile in LDS (XOR layout on 32B blocks), 16B coalesced stores
  __syncthreads();
  const int rgrp = (l >> 4) * 4;
  const float* bp = is_r ? br : bl;
  const int cb = (is_r ? colblk - 6 : colblk) * 128;
#pragma unroll
  for (int n = 0; n < 4; n++){
    int lc = wn + n * 16 + r0;
    float bb = bp[cb + lc];
#pragma unroll
    for (int m = 0; m < 4; m++){
#pragma unroll
      for (int jj = 0; jj < 4; jj++){
        int lr = wm + m * 16 + rgrp + jj;
        int byte = lr * 256 + ((lc * 2) ^ (((lr >> 2) & 3) << 5));
        *(__hip_bfloat16*)(smem + byte) = __float2bfloat16(acc[m][n][jj] + bb);
      }
    }
  }
  __syncthreads();
  __hip_bfloat16* C = is_r ? Cr : Cl;
#pragma unroll
  for (int p = 0; p < 8; p++){
    int ba = p * 4096 + t16;
    int lr = ba >> 8, inner = ba & 255;
    int gr = row0 + lr;
    if (!is_r && gr >= nrl) continue;          // past compacted count
    int orow = remap ? rmap[gr] : gr;
    uint4 v = *(const uint4*)(smem + lr * 256 + (inner ^ (((lr >> 2) & 3) << 5)));
    *(uint4*)(C + (size_t)orow * H + cb + (inner >> 1)) = v;
  }
}

// ---------------- edge helpers ----------------
__device__ __forceinline__ int e_src(const int* ep, int E0, int k){
  return (k < E0) ? ep[k] : (k - E0);
}
__device__ __forceinline__ int e_dst(const int* ep, int E0, int k){
  return (k < E0) ? ep[E0 + k] : (k - E0);
}

// ---------------- CSR build (by dst): count + hierarchical scan + fill ----------------
__global__ __launch_bounds__(256) void count_kernel(const int* __restrict__ ep,
                                                    int E0, int E, int* __restrict__ cnt){
  int k = blockIdx.x * 256 + threadIdx.x;
  if (k >= E) return;
  atomicAdd(&cnt[e_dst(ep, E0, k)], 1);
}

__global__ __launch_bounds__(1024) void scan1_kernel(const int* __restrict__ cnt,
                                                     int* __restrict__ off,
                                                     int* __restrict__ sums, int n){
  __shared__ int lds[1024];
  int tid = threadIdx.x;
  int gi = blockIdx.x * 1024 + tid;
  int v = (gi < n) ? cnt[gi] : 0;
  lds[tid] = v;
  __syncthreads();
  for (int o = 1; o < 1024; o <<= 1){
    int tv = (tid >= o) ? lds[tid - o] : 0;
    __syncthreads();
    lds[tid] += tv;
    __syncthreads();
  }
  if (gi < n) off[gi] = lds[tid] - v;          // exclusive within chunk
  if (tid == 1023) sums[blockIdx.x] = lds[1023];
}

__global__ void scan2_kernel(int* __restrict__ sums, int* __restrict__ off,
                             int nb, int n){
  int lane = threadIdx.x;                      // single wave of 64, nb <= 64
  int v = (lane < nb) ? sums[lane] : 0;
  int incl = v;
#pragma unroll
  for (int o = 1; o < 64; o <<= 1){
    int t = __shfl_up(incl, o);
    if (lane >= o) incl += t;
  }
  if (lane < nb) sums[lane] = incl - v;        // exclusive block offsets
  if (lane == nb - 1) off[n] = incl;           // grand total
}

__global__ __launch_bounds__(1024) void scan3_kernel(int* __restrict__ off,
                                                     int* __restrict__ cur,
                                                     const int* __restrict__ sums, int n){
  int gi = blockIdx.x * 1024 + threadIdx.x;
  if (gi < n){
    int v = off[gi] + sums[blockIdx.x];
    off[gi] = v;
    cur[gi] = v;
  }
}

__global__ __launch_bounds__(256) void fill_kernel(const int* __restrict__ ep, int E0, int E,
                                                   int* __restrict__ cur, int* __restrict__ csr){
  int k = blockIdx.x * 256 + threadIdx.x;
  if (k >= E) return;
  int d = e_dst(ep, E0, k);
  int pos = atomicAdd(&cur[d], 1);
  csr[pos] = k;
}

// ---------------- layer-2 row compaction: src nodes feeding dst < L ----------------
__global__ __launch_bounds__(256) void mark_kernel(const int* __restrict__ ep,
                                                   int E0, int E, int L,
                                                   int* __restrict__ flag){
  int k = blockIdx.x * 256 + threadIdx.x;
  if (k >= E) return;
  if (e_dst(ep, E0, k) >= L) return;
  flag[e_src(ep, E0, k)] = 1;                  // benign same-value race
}

__global__ __launch_bounds__(256) void compact_kernel(const int* __restrict__ flag,
                                                      int* __restrict__ list,
                                                      int* __restrict__ nrows, int n){
  int i = blockIdx.x * 256 + threadIdx.x;
  if (i >= n) return;
  if (flag[i]) list[atomicAdd(nrows, 1)] = i;
}

// ---------------- fused GAT attend+aggregate+LN+GELU: one WAVE per dst ----------------
template<typename OutT>
__global__ __launch_bounds__(256) void agat_kernel(
    const __hip_bfloat16* __restrict__ xl, const __hip_bfloat16* __restrict__ xr,
    const float* __restrict__ att, const int* __restrict__ off,
    const int* __restrict__ csr, const int* __restrict__ ep, int E0,
    const float* __restrict__ bias, const float* __restrict__ g,
    const float* __restrict__ b, OutT* __restrict__ out, int ndst){
  int d = blockIdx.x * 4 + (threadIdx.x >> 6);
  if (d >= ndst) return;
  int lane = threadIdx.x & 63;
  float xrv[12], attv[12];
  const unsigned* pr = (const unsigned*)(xr + (size_t)d * H);
#pragma unroll
  for (int i = 0; i < 3; i++){
    uint2 vr = *(const uint2*)&pr[lane * 2 + i * 128];
    float4 av = *(const float4*)&att[(lane + i * 64) * 4];
    xrv[i*4+0] = bf2f(vr.x); xrv[i*4+1] = bf2f(vr.x >> 16);
    xrv[i*4+2] = bf2f(vr.y); xrv[i*4+3] = bf2f(vr.y >> 16);
    attv[i*4+0] = av.x; attv[i*4+1] = av.y; attv[i*4+2] = av.z; attv[i*4+3] = av.w;
  }
  float m = -INFINITY, den = 0.f, acc[12];
#pragma unroll
  for (int t = 0; t < 12; t++) acc[t] = 0.f;
  int j0 = off[d], j1 = off[d + 1];
  for (int j = j0; j < j1; j++){
    int k = csr[j], s = e_src(ep, E0, k);
    const unsigned* pl = (const unsigned*)(xl + (size_t)s * H);
    float xv[12];
#pragma unroll
    for (int i = 0; i < 3; i++){
      uint2 vl = *(const uint2*)&pl[lane * 2 + i * 128];
      xv[i*4+0] = bf2f(vl.x); xv[i*4+1] = bf2f(vl.x >> 16);
      xv[i*4+2] = bf2f(vl.y); xv[i*4+3] = bf2f(vl.y >> 16);
    }
    float p = 0.f;
#pragma unroll
    for (int t = 0; t < 12; t++){
      float v = xv[t] + xrv[t];
      v = (v > 0.f) ? v : 0.2f * v;
      p += v * attv[t];
    }
    p = wave_sum(p);                      // all lanes hold edge score
    float mn = fmaxf(m, p);               // branchless online softmax
    float sc = __expf(m - mn), wgt = __expf(p - mn);
    den = den * sc + wgt;
#pragma unroll
    for (int t = 0; t < 12; t++) acc[t] = acc[t] * sc + wgt * xv[t];
    m = mn;
  }
  float inv = 1.0f / den;
  float y[12];
  float s1 = 0.f;
#pragma unroll
  for (int i = 0; i < 3; i++){
    float4 bv = *(const float4*)&bias[(lane + i * 64) * 4];
    y[i*4+0] = acc[i*4+0] * inv + bv.x;
    y[i*4+1] = acc[i*4+1] * inv + bv.y;
    y[i*4+2] = acc[i*4+2] * inv + bv.z;
    y[i*4+3] = acc[i*4+3] * inv + bv.w;
  }
#pragma unroll
  for (int t = 0; t < 12; t++) s1 += y[t];
  float mean = wave_sum(s1) * (1.0f / H);
  float s2 = 0.f;
#pragma unroll
  for (int t = 0; t < 12; t++){ float dt = y[t] - mean; s2 += dt * dt; }
  float rstd = rsqrtf(wave_sum(s2) * (1.0f / H) + 1e-5f);
  OutT* op = out + (size_t)d * H;
#pragma unroll
  for (int i = 0; i < 3; i++){
    float4 gv = *(const float4*)&g[(lane + i * 64) * 4];
    float4 bv = *(const float4*)&b[(lane + i * 64) * 4];
    float z0 = gelu_exact((y[i*4+0] - mean) * rstd * gv.x + bv.x);
    float z1 = gelu_exact((y[i*4+1] - mean) * rstd * gv.y + bv.y);
    float z2 = gelu_exact((y[i*4+2] - mean) * rstd * gv.z + bv.z);
    float z3 = gelu_exact((y[i*4+3] - mean) * rstd * gv.w + bv.w);
    if constexpr (sizeof(OutT) == 2){
      uint2 pk; pk.x = f2bf2(z0, z1); pk.y = f2bf2(z2, z3);
      *(uint2*)((unsigned*)op + lane * 2 + i * 128) = pk;
    } else {
      float4 fv; fv.x = z0; fv.y = z1; fv.z = z2; fv.w = z3;
      *(float4*)&op[(lane + i * 64) * 4] = fv;
    }
  }
}

extern "C" void kernel_launch(void* const* d_in, const int* in_sizes, int n_in,
                              void* d_out, int out_size, void* d_ws, size_t ws_size,
                              hipStream_t stream){
  const float* emb   = (const float*)d_in[0];
  const float* feats = (const float*)d_in[1];
  const int*   edges = (const int*)d_in[2];
  const float* Wl2 = (const float*)d_in[4],  *bl2 = (const float*)d_in[5];
  const float* Wr2 = (const float*)d_in[6],  *br2 = (const float*)d_in[7];
  const float* att2= (const float*)d_in[8],  *bias2=(const float*)d_in[9];
  const float* Wl3 = (const float*)d_in[10], *bl3 = (const float*)d_in[11];
  const float* Wr3 = (const float*)d_in[12], *br3 = (const float*)d_in[13];
  const float* att3= (const float*)d_in[14], *bias3=(const float*)d_in[15];
  const float* g1 = (const float*)d_in[16], *b1 = (const float*)d_in[17];
  const float* g2 = (const float*)d_in[18], *b2 = (const float*)d_in[19];
  const float* g3 = (const float*)d_in[20], *b3 = (const float*)d_in[21];

  const int N  = in_sizes[1] / H;             // 50000
  const int E0 = in_sizes[2] / 2;             // 100000
  const int E  = E0 + N;                      // 150000
  const int L  = 4096;                        // labels_size
  const int panels = ((N + BM - 1) / BM + 7) & ~7;   // 392 (multiple of 8)
  const int Mpad = panels * BM;                       // 50176
  const int nchunk = (N + 1023) / 1024;               // 49 (<= 64)

  __hip_bfloat16* ab  = (__hip_bfloat16*)d_ws;          // [Mpad][H] GEMM input
  __hip_bfloat16* xl  = ab + (size_t)Mpad * H;          // [Mpad][H]
  __hip_bfloat16* xr  = xl + (size_t)Mpad * H;          // [Mpad][H]
  __hip_bfloat16* wt2 = xr + (size_t)Mpad * H;          // [1536][H]
  __hip_bfloat16* wt3 = wt2 + (size_t)2 * H * H;        // [1536][H]
  int* cnt = (int*)(wt3 + (size_t)2 * H * H);
  int* off = cnt + N;
  int* cur = off + N + 1;
  int* csr = cur + N;
  int* sums = csr + E;
  int* flag = sums + 64;
  int* list = flag + N;
  int* nrows = list + N;

  float* out_f = (float*)d_out;

  // output 0: passthrough copy of input_embeddings
  hipMemcpyAsync(out_f, emb, (size_t)in_sizes[0] * sizeof(float),
                 hipMemcpyDeviceToDevice, stream);

  // CSR by dst (shared by both layers)
  hipMemsetAsync(cnt, 0, (size_t)N * sizeof(int), stream);
  count_kernel<<<(E + 255) / 256, 256, 0, stream>>>(edges, E0, E, cnt);
  scan1_kernel<<<nchunk, 1024, 0, stream>>>(cnt, off, sums, N);
  scan2_kernel<<<1, 64, 0, stream>>>(sums, off, nchunk, N);
  scan3_kernel<<<nchunk, 1024, 0, stream>>>(off, cur, sums, N);
  fill_kernel<<<(E + 255) / 256, 256, 0, stream>>>(edges, E0, E, cur, csr);

  // layer-2 xl row compaction: src nodes of edges with dst < L (+ self-loops < L)
  hipMemsetAsync(flag, 0, (size_t)(N + 1) * sizeof(int), stream);   // flag + nrows... (nrows separate)
  hipMemsetAsync(nrows, 0, sizeof(int), stream);
  mark_kernel<<<(E + 255) / 256, 256, 0, stream>>>(edges, E0, E, L, flag);
  compact_kernel<<<(N + 255) / 256, 256, 0, stream>>>(flag, list, nrows, N);

  // weights -> bf16 transposed, concatenated [Wl^T ; Wr^T]
  dim3 wgrid(H / 32, H / 32);
  wt_bf16_kernel<<<wgrid, 256, 0, stream>>>(Wl2, wt2);
  wt_bf16_kernel<<<wgrid, 256, 0, stream>>>(Wr2, wt2 + (size_t)H * H);
  wt_bf16_kernel<<<wgrid, 256, 0, stream>>>(Wl3, wt3);
  wt_bf16_kernel<<<wgrid, 256, 0, stream>>>(Wr3, wt3 + (size_t)H * H);

  const int gblocks = panels * 12;

  // ---- layer 1 (full N) ----
  lnw_kernel<<<(N + 3) / 4, 256, 0, stream>>>(feats, g1, b1, ab, N);
  gemm_fused_kernel<<<gblocks, 256, 0, stream>>>(ab, wt2, bl2, br2, xl, xr,
                                                 nullptr, nullptr, panels, Mpad);
  agat_kernel<__hip_bfloat16><<<(N + 3) / 4, 256, 0, stream>>>(
      xl, xr, att2, off, csr, edges, E0, bias2, g2, b2, ab, N);

  // ---- layer 2 (xl only for compacted src rows; xr + aggregation only rows < L) ----
  gemm_fused_kernel<<<gblocks, 256, 0, stream>>>(ab, wt3, bl3, br3, xl, xr,
                                                 list, nrows, panels, L);
  agat_kernel<float><<<(L + 3) / 4, 256, 0, stream>>>(
      xl, xr, att3, off, csr, edges, E0, bias3, g3, b3, out_f + in_sizes[0], L);
}

// Round 7
// 404.654 us; speedup vs baseline: 1.2197x; 1.2197x over previous
//
#include <hip/hip_runtime.h>
#include <hip/hip_bf16.h>
#include <math.h>

#define H 768
#define BM 128

typedef __attribute__((ext_vector_type(4))) float f32x4;
typedef __attribute__((ext_vector_type(8))) short bf16x8;

__device__ __forceinline__ float bf2f(unsigned u16v){
  return __uint_as_float((u16v & 0xffffu) << 16);
}
__device__ __forceinline__ unsigned f2bf2(float a, float b){
  __hip_bfloat16 ha = __float2bfloat16(a), hb = __float2bfloat16(b);
  return (unsigned)*(unsigned short*)&ha | ((unsigned)*(unsigned short*)&hb << 16);
}
__device__ __forceinline__ float gelu_exact(float x){
  return 0.5f * x * (1.0f + erff(x * 0.70710678118654752f));
}
__device__ __forceinline__ void gload16(const void* g, void* l){
  __builtin_amdgcn_global_load_lds(
      (const __attribute__((address_space(1))) unsigned int*)g,
      (__attribute__((address_space(3))) unsigned int*)l,
      16, 0, 0);
}
__device__ __forceinline__ float wave_sum(float p){
#pragma unroll
  for (int o = 32; o; o >>= 1) p += __shfl_xor(p, o);
  return p;
}

// ---------------- LayerNorm + exact GELU: one WAVE per row, f32 in, bf16 out ----------------
__global__ __launch_bounds__(256) void lnw_kernel(
    const float* __restrict__ in, const float* __restrict__ g,
    const float* __restrict__ b, __hip_bfloat16* __restrict__ out, int rows){
  int row = blockIdx.x * 4 + (threadIdx.x >> 6);
  if (row >= rows) return;
  int lane = threadIdx.x & 63;
  const float* rp = in + (size_t)row * H;
  float v[12];
#pragma unroll
  for (int i = 0; i < 3; i++){
    float4 t = *(const float4*)&rp[(lane + i * 64) * 4];
    v[i*4+0] = t.x; v[i*4+1] = t.y; v[i*4+2] = t.z; v[i*4+3] = t.w;
  }
  float s = 0.f;
#pragma unroll
  for (int t = 0; t < 12; t++) s += v[t];
  float mean = wave_sum(s) * (1.0f / H);
  float s2 = 0.f;
#pragma unroll
  for (int t = 0; t < 12; t++){ float d = v[t] - mean; s2 += d * d; }
  float rstd = rsqrtf(wave_sum(s2) * (1.0f / H) + 1e-5f);
  unsigned* op = (unsigned*)(out + (size_t)row * H);
#pragma unroll
  for (int i = 0; i < 3; i++){
    float4 gv = *(const float4*)&g[(lane + i * 64) * 4];
    float4 bv = *(const float4*)&b[(lane + i * 64) * 4];
    float z0 = gelu_exact((v[i*4+0] - mean) * rstd * gv.x + bv.x);
    float z1 = gelu_exact((v[i*4+1] - mean) * rstd * gv.y + bv.y);
    float z2 = gelu_exact((v[i*4+2] - mean) * rstd * gv.z + bv.z);
    float z3 = gelu_exact((v[i*4+3] - mean) * rstd * gv.w + bv.w);
    uint2 pk; pk.x = f2bf2(z0, z1); pk.y = f2bf2(z2, z3);
    *(uint2*)&op[lane * 2 + i * 128] = pk;
  }
}

// ---------------- weight transpose + f32->bf16: WT[n][k] = W[k][n] ----------------
__global__ __launch_bounds__(256) void wt_bf16_kernel(
    const float* __restrict__ W, __hip_bfloat16* __restrict__ WT){
  __shared__ float tile[32][33];
  int k0 = blockIdx.x * 32, n0 = blockIdx.y * 32;
  int tx = threadIdx.x & 31, ty = threadIdx.x >> 5;   // 32 x 8
#pragma unroll
  for (int i = 0; i < 32; i += 8)
    tile[ty + i][tx] = W[(size_t)(k0 + ty + i) * H + n0 + tx];
  __syncthreads();
#pragma unroll
  for (int i = 0; i < 32; i += 8)
    WT[(size_t)(n0 + ty + i) * H + k0 + tx] = __float2bfloat16(tile[tx][ty + i]);
}

// ---------------- fused bf16 MFMA GEMM, optional row-compaction indirection ----------------
// [Cl | Cr] = A[*,768] @ WT[1536,768]^T (+bias).
// remap mode (rmap != null): xl rows are rmap[row] for row < *nr_p; xr rows < Mr.
//   Block mapping is IDENTITY (panel = wgid/12) so active blocks spread across
//   all XCDs (dispatch round-robin); the XCD swizzle would pile them on XCD 0-1.
// identity mode: XCD-swizzled panels for A-panel L2 locality.
__global__ __launch_bounds__(256, 3) void gemm_fused_kernel(
    const __hip_bfloat16* __restrict__ A,
    const __hip_bfloat16* __restrict__ WT,
    const float* __restrict__ bl, const float* __restrict__ br,
    __hip_bfloat16* __restrict__ Cl, __hip_bfloat16* __restrict__ Cr,
    const int* __restrict__ rmap, const int* __restrict__ nr_p,
    int panels, int Mr){
  __shared__ char smem[49152];          // 3 x (As 8KB | Bs 8KB)

  int wgid = blockIdx.x;
  int panel, colblk;
  if (rmap){
    panel = wgid / 12; colblk = wgid % 12;
  } else {
    int xcd = wgid & 7, j = wgid >> 3;
    panel = xcd * (panels >> 3) + j / 12;
    colblk = j % 12;
  }
  int row0 = panel * BM;
  const bool is_r = colblk >= 6;
  int nrl = panels * BM;
  if (rmap && nr_p) nrl = *nr_p;                       // device-side compacted count
  if (is_r){ if (row0 >= Mr) return; }
  else     { if (row0 >= nrl) return; }
  const bool remap = (rmap != nullptr) && !is_r;

  const int t = threadIdx.x;
  const int sr = t >> 2;                               // staging row 0..63
  const int scs = (((t & 3) ^ ((sr >> 1) & 3)) * 8);   // pre-swizzled global col
  const int t16 = t * 16;                              // linear LDS byte slot
  int ra0 = row0 + sr, ra1 = row0 + sr + 64;
  if (remap){
    ra0 = rmap[min(ra0, nrl - 1)];
    ra1 = rmap[min(ra1, nrl - 1)];
  }
  const __hip_bfloat16* pa0 = A + (size_t)ra0 * H + scs;
  const __hip_bfloat16* pa1 = A + (size_t)ra1 * H + scs;
  const __hip_bfloat16* pb0 = WT + (size_t)(colblk * 128 + sr) * H + scs;
  const __hip_bfloat16* pb1 = pb0 + (size_t)64 * H;

  const int l = t & 63, w = t >> 6;
  const int wm = (w >> 1) * 64, wn = (w & 1) * 64;
  const int r0 = l & 15;
  const int kcs2 = (((l >> 4) ^ ((r0 >> 1) & 3)) * 16); // swizzled frag byte col

  f32x4 acc[4][4];
#pragma unroll
  for (int m = 0; m < 4; m++)
#pragma unroll
    for (int n = 0; n < 4; n++) acc[m][n] = (f32x4){0.f, 0.f, 0.f, 0.f};

#define STAGE(kt, b) do{                                   \
    int _k0 = (kt) * 32;                                   \
    char* _bs = smem + (b) * 16384;                        \
    gload16(pa0 + _k0, _bs + t16);                         \
    gload16(pa1 + _k0, _bs + 4096 + t16);                  \
    gload16(pb0 + _k0, _bs + 8192 + t16);                  \
    gload16(pb1 + _k0, _bs + 12288 + t16);                 \
  }while(0)

  STAGE(0, 0);
  STAGE(1, 1);

  for (int kt = 0; kt < 24; kt++){
    if (kt < 23) asm volatile("s_waitcnt vmcnt(4)" ::: "memory");
    else         asm volatile("s_waitcnt vmcnt(0)" ::: "memory");
    __builtin_amdgcn_s_barrier();
    __builtin_amdgcn_sched_barrier(0);
    if (kt + 2 < 24) STAGE(kt + 2, (kt + 2) % 3);
    const char* base = smem + (kt % 3) * 16384;
    bf16x8 af[4], bfr[4];
#pragma unroll
    for (int m = 0; m < 4; m++)
      af[m]  = *(const bf16x8*)(base + (wm + m * 16 + r0) * 64 + kcs2);
#pragma unroll
    for (int n = 0; n < 4; n++)
      bfr[n] = *(const bf16x8*)(base + 8192 + (wn + n * 16 + r0) * 64 + kcs2);
#pragma unroll
    for (int m = 0; m < 4; m++)
#pragma unroll
      for (int n = 0; n < 4; n++)
        acc[m][n] = __builtin_amdgcn_mfma_f32_16x16x32_bf16(af[m], bfr[n], acc[m][n], 0, 0, 0);
  }
#undef STAGE

  // epilogue: stage C tile in LDS (XOR layout on 32B blocks), 16B coalesced stores
  __syncthreads();
  const int rgrp = (l >> 4) * 4;
  const float* bp = is_r ? br : bl;
  const int cb = (is_r ? colblk - 6 : colblk) * 128;
#pragma unroll
  for (int n = 0; n < 4; n++){
    int lc = wn + n * 16 + r0;
    float bb = bp[cb + lc];
#pragma unroll
    for (int m = 0; m < 4; m++){
#pragma unroll
      for (int jj = 0; jj < 4; jj++){
        int lr = wm + m * 16 + rgrp + jj;
        int byte = lr * 256 + ((lc * 2) ^ (((lr >> 2) & 3) << 5));
        *(__hip_bfloat16*)(smem + byte) = __float2bfloat16(acc[m][n][jj] + bb);
      }
    }
  }
  __syncthreads();
  __hip_bfloat16* C = is_r ? Cr : Cl;
#pragma unroll
  for (int p = 0; p < 8; p++){
    int ba = p * 4096 + t16;
    int lr = ba >> 8, inner = ba & 255;
    int gr = row0 + lr;
    if (!is_r && gr >= nrl) continue;          // past compacted count
    int orow = remap ? rmap[gr] : gr;
    uint4 v = *(const uint4*)(smem + lr * 256 + (inner ^ (((lr >> 2) & 3) << 5)));
    *(uint4*)(C + (size_t)orow * H + cb + (inner >> 1)) = v;
  }
}

// ---------------- edge helpers ----------------
__device__ __forceinline__ int e_src(const int* ep, int E0, int k){
  return (k < E0) ? ep[k] : (k - E0);
}
__device__ __forceinline__ int e_dst(const int* ep, int E0, int k){
  return (k < E0) ? ep[E0 + k] : (k - E0);
}

// ---------------- CSR build + layer-2 src marking (fused) ----------------
__global__ __launch_bounds__(256) void count_mark_kernel(const int* __restrict__ ep,
                                                         int E0, int E, int L,
                                                         int* __restrict__ cnt,
                                                         int* __restrict__ flag){
  int k = blockIdx.x * 256 + threadIdx.x;
  if (k >= E) return;
  int d = e_dst(ep, E0, k);
  atomicAdd(&cnt[d], 1);
  if (d < L) flag[e_src(ep, E0, k)] = 1;       // benign same-value race
}

__global__ __launch_bounds__(1024) void scan1_kernel(const int* __restrict__ cnt,
                                                     int* __restrict__ off,
                                                     int* __restrict__ sums, int n){
  __shared__ int lds[1024];
  int tid = threadIdx.x;
  int gi = blockIdx.x * 1024 + tid;
  int v = (gi < n) ? cnt[gi] : 0;
  lds[tid] = v;
  __syncthreads();
  for (int o = 1; o < 1024; o <<= 1){
    int tv = (tid >= o) ? lds[tid - o] : 0;
    __syncthreads();
    lds[tid] += tv;
    __syncthreads();
  }
  if (gi < n) off[gi] = lds[tid] - v;          // exclusive within chunk
  if (tid == 1023) sums[blockIdx.x] = lds[1023];
}

__global__ void scan2_kernel(int* __restrict__ sums, int* __restrict__ off,
                             int nb, int n){
  int lane = threadIdx.x;                      // single wave of 64, nb <= 64
  int v = (lane < nb) ? sums[lane] : 0;
  int incl = v;
#pragma unroll
  for (int o = 1; o < 64; o <<= 1){
    int t = __shfl_up(incl, o);
    if (lane >= o) incl += t;
  }
  if (lane < nb) sums[lane] = incl - v;        // exclusive block offsets
  if (lane == nb - 1) off[n] = incl;           // grand total
}

__global__ __launch_bounds__(1024) void scan3_kernel(int* __restrict__ off,
                                                     int* __restrict__ cur,
                                                     const int* __restrict__ sums, int n){
  int gi = blockIdx.x * 1024 + threadIdx.x;
  if (gi < n){
    int v = off[gi] + sums[blockIdx.x];
    off[gi] = v;
    cur[gi] = v;
  }
}

// ordered compaction writer: list[exscan(flag)[i]] = i (deterministic, sorted)
__global__ __launch_bounds__(1024) void flist_kernel(const int* __restrict__ flag,
                                                     const int* __restrict__ fpos,
                                                     const int* __restrict__ fsums,
                                                     int* __restrict__ list, int n){
  int gi = blockIdx.x * 1024 + threadIdx.x;
  if (gi < n && flag[gi]) list[fpos[gi] + fsums[blockIdx.x]] = gi;
}

__global__ __launch_bounds__(256) void fill_kernel(const int* __restrict__ ep, int E0, int E,
                                                   int* __restrict__ cur, int* __restrict__ csr){
  int k = blockIdx.x * 256 + threadIdx.x;
  if (k >= E) return;
  int d = e_dst(ep, E0, k);
  int pos = atomicAdd(&cur[d], 1);
  csr[pos] = k;
}

// ---------------- fused GAT attend+aggregate+LN+GELU: one WAVE per dst ----------------
template<typename OutT>
__global__ __launch_bounds__(256) void agat_kernel(
    const __hip_bfloat16* __restrict__ xl, const __hip_bfloat16* __restrict__ xr,
    const float* __restrict__ att, const int* __restrict__ off,
    const int* __restrict__ csr, const int* __restrict__ ep, int E0,
    const float* __restrict__ bias, const float* __restrict__ g,
    const float* __restrict__ b, OutT* __restrict__ out, int ndst){
  int d = blockIdx.x * 4 + (threadIdx.x >> 6);
  if (d >= ndst) return;
  int lane = threadIdx.x & 63;
  float xrv[12], attv[12];
  const unsigned* pr = (const unsigned*)(xr + (size_t)d * H);
#pragma unroll
  for (int i = 0; i < 3; i++){
    uint2 vr = *(const uint2*)&pr[lane * 2 + i * 128];
    float4 av = *(const float4*)&att[(lane + i * 64) * 4];
    xrv[i*4+0] = bf2f(vr.x); xrv[i*4+1] = bf2f(vr.x >> 16);
    xrv[i*4+2] = bf2f(vr.y); xrv[i*4+3] = bf2f(vr.y >> 16);
    attv[i*4+0] = av.x; attv[i*4+1] = av.y; attv[i*4+2] = av.z; attv[i*4+3] = av.w;
  }
  float m = -INFINITY, den = 0.f, acc[12];
#pragma unroll
  for (int t = 0; t < 12; t++) acc[t] = 0.f;
  int j0 = off[d], j1 = off[d + 1];
  for (int j = j0; j < j1; j++){
    int k = csr[j], s = e_src(ep, E0, k);
    const unsigned* pl = (const unsigned*)(xl + (size_t)s * H);
    float xv[12];
#pragma unroll
    for (int i = 0; i < 3; i++){
      uint2 vl = *(const uint2*)&pl[lane * 2 + i * 128];
      xv[i*4+0] = bf2f(vl.x); xv[i*4+1] = bf2f(vl.x >> 16);
      xv[i*4+2] = bf2f(vl.y); xv[i*4+3] = bf2f(vl.y >> 16);
    }
    float p = 0.f;
#pragma unroll
    for (int t = 0; t < 12; t++){
      float v = xv[t] + xrv[t];
      v = (v > 0.f) ? v : 0.2f * v;
      p += v * attv[t];
    }
    p = wave_sum(p);                      // all lanes hold edge score
    float mn = fmaxf(m, p);               // branchless online softmax
    float sc = __expf(m - mn), wgt = __expf(p - mn);
    den = den * sc + wgt;
#pragma unroll
    for (int t = 0; t < 12; t++) acc[t] = acc[t] * sc + wgt * xv[t];
    m = mn;
  }
  float inv = 1.0f / den;
  float y[12];
  float s1 = 0.f;
#pragma unroll
  for (int i = 0; i < 3; i++){
    float4 bv = *(const float4*)&bias[(lane + i * 64) * 4];
    y[i*4+0] = acc[i*4+0] * inv + bv.x;
    y[i*4+1] = acc[i*4+1] * inv + bv.y;
    y[i*4+2] = acc[i*4+2] * inv + bv.z;
    y[i*4+3] = acc[i*4+3] * inv + bv.w;
  }
#pragma unroll
  for (int t = 0; t < 12; t++) s1 += y[t];
  float mean = wave_sum(s1) * (1.0f / H);
  float s2 = 0.f;
#pragma unroll
  for (int t = 0; t < 12; t++){ float dt = y[t] - mean; s2 += dt * dt; }
  float rstd = rsqrtf(wave_sum(s2) * (1.0f / H) + 1e-5f);
  OutT* op = out + (size_t)d * H;
#pragma unroll
  for (int i = 0; i < 3; i++){
    float4 gv = *(const float4*)&g[(lane + i * 64) * 4];
    float4 bv = *(const float4*)&b[(lane + i * 64) * 4];
    float z0 = gelu_exact((y[i*4+0] - mean) * rstd * gv.x + bv.x);
    float z1 = gelu_exact((y[i*4+1] - mean) * rstd * gv.y + bv.y);
    float z2 = gelu_exact((y[i*4+2] - mean) * rstd * gv.z + bv.z);
    float z3 = gelu_exact((y[i*4+3] - mean) * rstd * gv.w + bv.w);
    if constexpr (sizeof(OutT) == 2){
      uint2 pk; pk.x = f2bf2(z0, z1); pk.y = f2bf2(z2, z3);
      *(uint2*)((unsigned*)op + lane * 2 + i * 128) = pk;
    } else {
      float4 fv; fv.x = z0; fv.y = z1; fv.z = z2; fv.w = z3;
      *(float4*)&op[(lane + i * 64) * 4] = fv;
    }
  }
}

extern "C" void kernel_launch(void* const* d_in, const int* in_sizes, int n_in,
                              void* d_out, int out_size, void* d_ws, size_t ws_size,
                              hipStream_t stream){
  const float* emb   = (const float*)d_in[0];
  const float* feats = (const float*)d_in[1];
  const int*   edges = (const int*)d_in[2];
  const float* Wl2 = (const float*)d_in[4],  *bl2 = (const float*)d_in[5];
  const float* Wr2 = (const float*)d_in[6],  *br2 = (const float*)d_in[7];
  const float* att2= (const float*)d_in[8],  *bias2=(const float*)d_in[9];
  const float* Wl3 = (const float*)d_in[10], *bl3 = (const float*)d_in[11];
  const float* Wr3 = (const float*)d_in[12], *br3 = (const float*)d_in[13];
  const float* att3= (const float*)d_in[14], *bias3=(const float*)d_in[15];
  const float* g1 = (const float*)d_in[16], *b1 = (const float*)d_in[17];
  const float* g2 = (const float*)d_in[18], *b2 = (const float*)d_in[19];
  const float* g3 = (const float*)d_in[20], *b3 = (const float*)d_in[21];

  const int N  = in_sizes[1] / H;             // 50000
  const int E0 = in_sizes[2] / 2;             // 100000
  const int E  = E0 + N;                      // 150000
  const int L  = 4096;                        // labels_size
  const int panels = ((N + BM - 1) / BM + 7) & ~7;   // 392 (multiple of 8)
  const int Mpad = panels * BM;                       // 50176
  const int nchunk = (N + 1023) / 1024;               // 49 (<= 64)

  __hip_bfloat16* ab  = (__hip_bfloat16*)d_ws;          // [Mpad][H] GEMM input
  __hip_bfloat16* xl  = ab + (size_t)Mpad * H;          // [Mpad][H]
  __hip_bfloat16* xr  = xl + (size_t)Mpad * H;          // [Mpad][H]
  __hip_bfloat16* wt2 = xr + (size_t)Mpad * H;          // [1536][H]
  __hip_bfloat16* wt3 = wt2 + (size_t)2 * H * H;        // [1536][H]
  int* cnt  = (int*)(wt3 + (size_t)2 * H * H);          // [N]
  int* flag = cnt + N;                                  // [N] (contiguous w/ cnt for one memset)
  int* off  = flag + N;                                 // [N+1]
  int* cur  = off + N + 1;                              // [N]
  int* csr  = cur + N;                                  // [E]
  int* sums = csr + E;                                  // [64]
  int* fpos = sums + 64;                                // [N+1]
  int* fsums= fpos + N + 1;                             // [64]
  int* list = fsums + 64;                               // [N]

  float* out_f = (float*)d_out;

  // output 0: passthrough copy of input_embeddings
  hipMemcpyAsync(out_f, emb, (size_t)in_sizes[0] * sizeof(float),
                 hipMemcpyDeviceToDevice, stream);

  // CSR by dst + layer-2 src flags (one pass over edges)
  hipMemsetAsync(cnt, 0, (size_t)2 * N * sizeof(int), stream);
  count_mark_kernel<<<(E + 255) / 256, 256, 0, stream>>>(edges, E0, E, L, cnt, flag);
  scan1_kernel<<<nchunk, 1024, 0, stream>>>(cnt, off, sums, N);
  scan2_kernel<<<1, 64, 0, stream>>>(sums, off, nchunk, N);
  scan3_kernel<<<nchunk, 1024, 0, stream>>>(off, cur, sums, N);
  fill_kernel<<<(E + 255) / 256, 256, 0, stream>>>(edges, E0, E, cur, csr);
  // ordered compaction of flagged src rows -> list, count in fpos[N]
  scan1_kernel<<<nchunk, 1024, 0, stream>>>(flag, fpos, fsums, N);
  scan2_kernel<<<1, 64, 0, stream>>>(fsums, fpos, nchunk, N);
  flist_kernel<<<nchunk, 1024, 0, stream>>>(flag, fpos, fsums, list, N);

  // weights -> bf16 transposed, concatenated [Wl^T ; Wr^T]
  dim3 wgrid(H / 32, H / 32);
  wt_bf16_kernel<<<wgrid, 256, 0, stream>>>(Wl2, wt2);
  wt_bf16_kernel<<<wgrid, 256, 0, stream>>>(Wr2, wt2 + (size_t)H * H);
  wt_bf16_kernel<<<wgrid, 256, 0, stream>>>(Wl3, wt3);
  wt_bf16_kernel<<<wgrid, 256, 0, stream>>>(Wr3, wt3 + (size_t)H * H);

  const int gblocks = panels * 12;

  // ---- layer 1 (full N) ----
  lnw_kernel<<<(N + 3) / 4, 256, 0, stream>>>(feats, g1, b1, ab, N);
  gemm_fused_kernel<<<gblocks, 256, 0, stream>>>(ab, wt2, bl2, br2, xl, xr,
                                                 nullptr, nullptr, panels, Mpad);
  agat_kernel<__hip_bfloat16><<<(N + 3) / 4, 256, 0, stream>>>(
      xl, xr, att2, off, csr, edges, E0, bias2, g2, b2, ab, N);

  // ---- layer 2 (xl only for compacted src rows; xr + aggregation only rows < L) ----
  gemm_fused_kernel<<<gblocks, 256, 0, stream>>>(ab, wt3, bl3, br3, xl, xr,
                                                 list, fpos + N, panels, L);
  agat_kernel<float><<<(L + 3) / 4, 256, 0, stream>>>(
      xl, xr, att3, off, csr, edges, E0, bias3, g3, b3, out_f + in_sizes[0], L);
}

// Round 9
// 403.174 us; speedup vs baseline: 1.2241x; 1.0037x over previous
//
#include <hip/hip_runtime.h>
#include <hip/hip_bf16.h>
#include <math.h>

#define H 768
#define BM 128

typedef __attribute__((ext_vector_type(4))) float f32x4;
typedef __attribute__((ext_vector_type(8))) short bf16x8;

__device__ __forceinline__ float bf2f(unsigned u16v){
  return __uint_as_float((u16v & 0xffffu) << 16);
}
__device__ __forceinline__ unsigned f2bf2(float a, float b){
  __hip_bfloat16 ha = __float2bfloat16(a), hb = __float2bfloat16(b);
  return (unsigned)*(unsigned short*)&ha | ((unsigned)*(unsigned short*)&hb << 16);
}
__device__ __forceinline__ float gelu_exact(float x){
  return 0.5f * x * (1.0f + erff(x * 0.70710678118654752f));
}
__device__ __forceinline__ void gload16(const void* g, void* l){
  __builtin_amdgcn_global_load_lds(
      (const __attribute__((address_space(1))) unsigned int*)g,
      (__attribute__((address_space(3))) unsigned int*)l,
      16, 0, 0);
}
__device__ __forceinline__ float wave_sum(float p){
#pragma unroll
  for (int o = 32; o; o >>= 1) p += __shfl_xor(p, o);
  return p;
}

// ---------------- LayerNorm + exact GELU: one WAVE per row, f32 in, bf16 out ----------------
__global__ __launch_bounds__(256) void lnw_kernel(
    const float* __restrict__ in, const float* __restrict__ g,
    const float* __restrict__ b, __hip_bfloat16* __restrict__ out, int rows){
  int row = blockIdx.x * 4 + (threadIdx.x >> 6);
  if (row >= rows) return;
  int lane = threadIdx.x & 63;
  const float* rp = in + (size_t)row * H;
  float v[12];
#pragma unroll
  for (int i = 0; i < 3; i++){
    float4 t = *(const float4*)&rp[(lane + i * 64) * 4];
    v[i*4+0] = t.x; v[i*4+1] = t.y; v[i*4+2] = t.z; v[i*4+3] = t.w;
  }
  float s = 0.f;
#pragma unroll
  for (int t = 0; t < 12; t++) s += v[t];
  float mean = wave_sum(s) * (1.0f / H);
  float s2 = 0.f;
#pragma unroll
  for (int t = 0; t < 12; t++){ float d = v[t] - mean; s2 += d * d; }
  float rstd = rsqrtf(wave_sum(s2) * (1.0f / H) + 1e-5f);
  unsigned* op = (unsigned*)(out + (size_t)row * H);
#pragma unroll
  for (int i = 0; i < 3; i++){
    float4 gv = *(const float4*)&g[(lane + i * 64) * 4];
    float4 bv = *(const float4*)&b[(lane + i * 64) * 4];
    float z0 = gelu_exact((v[i*4+0] - mean) * rstd * gv.x + bv.x);
    float z1 = gelu_exact((v[i*4+1] - mean) * rstd * gv.y + bv.y);
    float z2 = gelu_exact((v[i*4+2] - mean) * rstd * gv.z + bv.z);
    float z3 = gelu_exact((v[i*4+3] - mean) * rstd * gv.w + bv.w);
    uint2 pk; pk.x = f2bf2(z0, z1); pk.y = f2bf2(z2, z3);
    *(uint2*)&op[lane * 2 + i * 128] = pk;
  }
}

// ---------------- weight transpose + f32->bf16: WT[n][k] = W[k][n] ----------------
__global__ __launch_bounds__(256) void wt_bf16_kernel(
    const float* __restrict__ W, __hip_bfloat16* __restrict__ WT){
  __shared__ float tile[32][33];
  int k0 = blockIdx.x * 32, n0 = blockIdx.y * 32;
  int tx = threadIdx.x & 31, ty = threadIdx.x >> 5;   // 32 x 8
#pragma unroll
  for (int i = 0; i < 32; i += 8)
    tile[ty + i][tx] = W[(size_t)(k0 + ty + i) * H + n0 + tx];
  __syncthreads();
#pragma unroll
  for (int i = 0; i < 32; i += 8)
    WT[(size_t)(n0 + ty + i) * H + k0 + tx] = __float2bfloat16(tile[tx][ty + i]);
}

// ---------------- 256x256 8-wave bf16 MFMA GEMM (layer 1, full M) ----------------
// [Cl | Cr] = A[196*256,768] @ WT[1536,768]^T (+bias). BK=32, PROVEN 3-buffer
// depth-2 counted-vmcnt pipeline (same counts as the validated 128^2 kernel),
// XOR swizzle, bijective XCD mapping, LDS-staged C epilogue. 128KB LDS, 8 waves.
// Staging rows >= Nrows clamp-read row Nrows-1 (outputs for them never consumed).
__global__ __launch_bounds__(512, 2) void gemm256_kernel(
    const __hip_bfloat16* __restrict__ A,
    const __hip_bfloat16* __restrict__ WT,
    const float* __restrict__ bl, const float* __restrict__ br,
    __hip_bfloat16* __restrict__ Cl, __hip_bfloat16* __restrict__ Cr,
    int panels, int Nrows){
  __shared__ char smem[131072];         // pipeline: 3 x 32KB; epilogue C: 128KB

  // bijective XCD-contiguous mapping: total blocks = panels*6 (divisible by 8)
  int spp = (panels * 6) >> 3;          // slots per XCD (147 for 196 panels)
  int s = (blockIdx.x & 7) * spp + (blockIdx.x >> 3);
  int panel = s / 6, colblk = s % 6;
  int row0 = panel * 256;
  const bool is_r = colblk >= 3;

  const int t = threadIdx.x;
  const int sr = t >> 2;                               // staging row 0..127
  const int scs = (((t & 3) ^ ((sr >> 1) & 3)) * 8);   // pre-swizzled global col
  const int t16 = t * 16;
  int ra0 = min(row0 + sr, Nrows - 1);
  int ra1 = min(row0 + sr + 128, Nrows - 1);
  const __hip_bfloat16* pa0 = A + (size_t)ra0 * H + scs;
  const __hip_bfloat16* pa1 = A + (size_t)ra1 * H + scs;
  const __hip_bfloat16* pb0 = WT + (size_t)(colblk * 256 + sr) * H + scs;
  const __hip_bfloat16* pb1 = pb0 + (size_t)128 * H;

  const int l = t & 63, w = t >> 6;
  const int wr = w >> 2, wc = w & 3;                   // 2 x 4 waves, 128x64 each
  const int r0 = l & 15;
  const int kcs2 = (((l >> 4) ^ ((r0 >> 1) & 3)) * 16);
  const int abase = wr * 8192;                          // A half select
  const int bbase = 16384 + wc * 4096;                  // B 64-row slice

  f32x4 acc[8][4];
#pragma unroll
  for (int m = 0; m < 8; m++)
#pragma unroll
    for (int n = 0; n < 4; n++) acc[m][n] = (f32x4){0.f, 0.f, 0.f, 0.f};

#define STAGE256(kt, b) do{                                \
    int _k0 = (kt) * 32;                                   \
    char* _bs = smem + (b) * 32768;                        \
    gload16(pa0 + _k0, _bs + t16);                         \
    gload16(pa1 + _k0, _bs + 8192 + t16);                  \
    gload16(pb0 + _k0, _bs + 16384 + t16);                 \
    gload16(pb1 + _k0, _bs + 24576 + t16);                 \
  }while(0)

  STAGE256(0, 0);
  STAGE256(1, 1);

  for (int kt = 0; kt < 24; kt++){
    if (kt < 23) asm volatile("s_waitcnt vmcnt(4) lgkmcnt(0)" ::: "memory");
    else         asm volatile("s_waitcnt vmcnt(0) lgkmcnt(0)" ::: "memory");
    __builtin_amdgcn_s_barrier();
    __builtin_amdgcn_sched_barrier(0);
    if (kt + 2 < 24) STAGE256(kt + 2, (kt + 2) % 3);
    const char* base = smem + (kt % 3) * 32768;
    bf16x8 af[8], bfr[4];
#pragma unroll
    for (int m = 0; m < 8; m++)
      af[m]  = *(const bf16x8*)(base + abase + (m * 16 + r0) * 64 + kcs2);
#pragma unroll
    for (int n = 0; n < 4; n++)
      bfr[n] = *(const bf16x8*)(base + bbase + (n * 16 + r0) * 64 + kcs2);
#pragma unroll
    for (int m = 0; m < 8; m++)
#pragma unroll
      for (int n = 0; n < 4; n++)
        acc[m][n] = __builtin_amdgcn_mfma_f32_16x16x32_bf16(af[m], bfr[n], acc[m][n], 0, 0, 0);
  }
#undef STAGE256

  // epilogue: stage C (256 x 512B rows) in LDS with 32B-chunk XOR, 16B stores
  __syncthreads();
  const int rgrp = (l >> 4) * 4;
  const int colblk2 = is_r ? colblk - 3 : colblk;
  const float* bp = is_r ? br : bl;
  const int cb = colblk2 * 256;
#pragma unroll
  for (int n = 0; n < 4; n++){
    int lc = wc * 64 + n * 16 + r0;
    float bb = bp[cb + lc];
#pragma unroll
    for (int m = 0; m < 8; m++){
#pragma unroll
      for (int jj = 0; jj < 4; jj++){
        int lr = wr * 128 + m * 16 + rgrp + jj;
        int byte = lr * 512 + ((lc * 2) ^ (((lr >> 2) & 3) << 5));
        *(__hip_bfloat16*)(smem + byte) = __float2bfloat16(acc[m][n][jj] + bb);
      }
    }
  }
  __syncthreads();
  __hip_bfloat16* C = is_r ? Cr : Cl;
#pragma unroll
  for (int p = 0; p < 16; p++){
    int ba = p * 8192 + t16;
    int lr = ba >> 9, inner = ba & 511;
    uint4 v = *(const uint4*)(smem + lr * 512 + (inner ^ (((lr >> 2) & 3) << 5)));
    *(uint4*)(C + (size_t)(row0 + lr) * H + cb + (inner >> 1)) = v;
  }
}

// ---------------- 128x128 4-wave GEMM with row-compaction (layer 2) ----------------
__global__ __launch_bounds__(256, 3) void gemm_fused_kernel(
    const __hip_bfloat16* __restrict__ A,
    const __hip_bfloat16* __restrict__ WT,
    const float* __restrict__ bl, const float* __restrict__ br,
    __hip_bfloat16* __restrict__ Cl, __hip_bfloat16* __restrict__ Cr,
    const int* __restrict__ rmap, const int* __restrict__ nr_p,
    int panels, int Mr){
  __shared__ char smem[49152];          // 3 x (As 8KB | Bs 8KB)

  int wgid = blockIdx.x;
  int panel = wgid / 12, colblk = wgid % 12;   // identity: spreads active blocks
  int row0 = panel * BM;
  const bool is_r = colblk >= 6;
  int nrl = *nr_p;
  if (is_r){ if (row0 >= Mr) return; }
  else     { if (row0 >= nrl) return; }
  const bool remap = !is_r;

  const int t = threadIdx.x;
  const int sr = t >> 2;
  const int scs = (((t & 3) ^ ((sr >> 1) & 3)) * 8);
  const int t16 = t * 16;
  int ra0 = row0 + sr, ra1 = row0 + sr + 64;
  if (remap){
    ra0 = rmap[min(ra0, nrl - 1)];
    ra1 = rmap[min(ra1, nrl - 1)];
  }
  const __hip_bfloat16* pa0 = A + (size_t)ra0 * H + scs;
  const __hip_bfloat16* pa1 = A + (size_t)ra1 * H + scs;
  const __hip_bfloat16* pb0 = WT + (size_t)(colblk * 128 + sr) * H + scs;
  const __hip_bfloat16* pb1 = pb0 + (size_t)64 * H;

  const int l = t & 63, w = t >> 6;
  const int wm = (w >> 1) * 64, wn = (w & 1) * 64;
  const int r0 = l & 15;
  const int kcs2 = (((l >> 4) ^ ((r0 >> 1) & 3)) * 16);

  f32x4 acc[4][4];
#pragma unroll
  for (int m = 0; m < 4; m++)
#pragma unroll
    for (int n = 0; n < 4; n++) acc[m][n] = (f32x4){0.f, 0.f, 0.f, 0.f};

#define STAGE(kt, b) do{                                   \
    int _k0 = (kt) * 32;                                   \
    char* _bs = smem + (b) * 16384;                        \
    gload16(pa0 + _k0, _bs + t16);                         \
    gload16(pa1 + _k0, _bs + 4096 + t16);                  \
    gload16(pb0 + _k0, _bs + 8192 + t16);                  \
    gload16(pb1 + _k0, _bs + 12288 + t16);                 \
  }while(0)

  STAGE(0, 0);
  STAGE(1, 1);

  for (int kt = 0; kt < 24; kt++){
    if (kt < 23) asm volatile("s_waitcnt vmcnt(4)" ::: "memory");
    else         asm volatile("s_waitcnt vmcnt(0)" ::: "memory");
    __builtin_amdgcn_s_barrier();
    __builtin_amdgcn_sched_barrier(0);
    if (kt + 2 < 24) STAGE(kt + 2, (kt + 2) % 3);
    const char* base = smem + (kt % 3) * 16384;
    bf16x8 af[4], bfr[4];
#pragma unroll
    for (int m = 0; m < 4; m++)
      af[m]  = *(const bf16x8*)(base + (wm + m * 16 + r0) * 64 + kcs2);
#pragma unroll
    for (int n = 0; n < 4; n++)
      bfr[n] = *(const bf16x8*)(base + 8192 + (wn + n * 16 + r0) * 64 + kcs2);
#pragma unroll
    for (int m = 0; m < 4; m++)
#pragma unroll
      for (int n = 0; n < 4; n++)
        acc[m][n] = __builtin_amdgcn_mfma_f32_16x16x32_bf16(af[m], bfr[n], acc[m][n], 0, 0, 0);
  }
#undef STAGE

  __syncthreads();
  const int rgrp = (l >> 4) * 4;
  const float* bp = is_r ? br : bl;
  const int cb = (is_r ? colblk - 6 : colblk) * 128;
#pragma unroll
  for (int n = 0; n < 4; n++){
    int lc = wn + n * 16 + r0;
    float bb = bp[cb + lc];
#pragma unroll
    for (int m = 0; m < 4; m++){
#pragma unroll
      for (int jj = 0; jj < 4; jj++){
        int lr = wm + m * 16 + rgrp + jj;
        int byte = lr * 256 + ((lc * 2) ^ (((lr >> 2) & 3) << 5));
        *(__hip_bfloat16*)(smem + byte) = __float2bfloat16(acc[m][n][jj] + bb);
      }
    }
  }
  __syncthreads();
  __hip_bfloat16* C = is_r ? Cr : Cl;
#pragma unroll
  for (int p = 0; p < 8; p++){
    int ba = p * 4096 + t16;
    int lr = ba >> 8, inner = ba & 255;
    int gr = row0 + lr;
    if (!is_r && gr >= nrl) continue;
    int orow = remap ? rmap[gr] : gr;
    uint4 v = *(const uint4*)(smem + lr * 256 + (inner ^ (((lr >> 2) & 3) << 5)));
    *(uint4*)(C + (size_t)orow * H + cb + (inner >> 1)) = v;
  }
}

// ---------------- edge helpers ----------------
__device__ __forceinline__ int e_src(const int* ep, int E0, int k){
  return (k < E0) ? ep[k] : (k - E0);
}
__device__ __forceinline__ int e_dst(const int* ep, int E0, int k){
  return (k < E0) ? ep[E0 + k] : (k - E0);
}

// ---------------- CSR build + layer-2 src marking (fused) ----------------
__global__ __launch_bounds__(256) void count_mark_kernel(const int* __restrict__ ep,
                                                         int E0, int E, int L,
                                                         int* __restrict__ cnt,
                                                         int* __restrict__ flag){
  int k = blockIdx.x * 256 + threadIdx.x;
  if (k >= E) return;
  int d = e_dst(ep, E0, k);
  atomicAdd(&cnt[d], 1);
  if (d < L) flag[e_src(ep, E0, k)] = 1;       // benign same-value race
}

__global__ __launch_bounds__(1024) void scan1_kernel(const int* __restrict__ cnt,
                                                     int* __restrict__ off,
                                                     int* __restrict__ sums, int n){
  __shared__ int lds[1024];
  int tid = threadIdx.x;
  int gi = blockIdx.x * 1024 + tid;
  int v = (gi < n) ? cnt[gi] : 0;
  lds[tid] = v;
  __syncthreads();
  for (int o = 1; o < 1024; o <<= 1){
    int tv = (tid >= o) ? lds[tid - o] : 0;
    __syncthreads();
    lds[tid] += tv;
    __syncthreads();
  }
  if (gi < n) off[gi] = lds[tid] - v;
  if (tid == 1023) sums[blockIdx.x] = lds[1023];
}

__global__ void scan2_kernel(int* __restrict__ sums, int* __restrict__ off,
                             int nb, int n){
  int lane = threadIdx.x;                      // single wave of 64, nb <= 64
  int v = (lane < nb) ? sums[lane] : 0;
  int incl = v;
#pragma unroll
  for (int o = 1; o < 64; o <<= 1){
    int t = __shfl_up(incl, o);
    if (lane >= o) incl += t;
  }
  if (lane < nb) sums[lane] = incl - v;
  if (lane == nb - 1) off[n] = incl;
}

__global__ __launch_bounds__(1024) void scan3_kernel(int* __restrict__ off,
                                                     int* __restrict__ cur,
                                                     const int* __restrict__ sums, int n){
  int gi = blockIdx.x * 1024 + threadIdx.x;
  if (gi < n){
    int v = off[gi] + sums[blockIdx.x];
    off[gi] = v;
    cur[gi] = v;
  }
}

__global__ __launch_bounds__(1024) void flist_kernel(const int* __restrict__ flag,
                                                     const int* __restrict__ fpos,
                                                     const int* __restrict__ fsums,
                                                     int* __restrict__ list, int n){
  int gi = blockIdx.x * 1024 + threadIdx.x;
  if (gi < n && flag[gi]) list[fpos[gi] + fsums[blockIdx.x]] = gi;
}

__global__ __launch_bounds__(256) void fill_kernel(const int* __restrict__ ep, int E0, int E,
                                                   int* __restrict__ cur, int* __restrict__ csr){
  int k = blockIdx.x * 256 + threadIdx.x;
  if (k >= E) return;
  int d = e_dst(ep, E0, k);
  int pos = atomicAdd(&cur[d], 1);
  csr[pos] = k;
}

// ---------------- fused GAT attend+aggregate+LN+GELU: one WAVE per dst ----------------
template<typename OutT>
__global__ __launch_bounds__(256) void agat_kernel(
    const __hip_bfloat16* __restrict__ xl, const __hip_bfloat16* __restrict__ xr,
    const float* __restrict__ att, const int* __restrict__ off,
    const int* __restrict__ csr, const int* __restrict__ ep, int E0,
    const float* __restrict__ bias, const float* __restrict__ g,
    const float* __restrict__ b, OutT* __restrict__ out, int ndst){
  int d = blockIdx.x * 4 + (threadIdx.x >> 6);
  if (d >= ndst) return;
  int lane = threadIdx.x & 63;
  float xrv[12], attv[12];
  const unsigned* pr = (const unsigned*)(xr + (size_t)d * H);
#pragma unroll
  for (int i = 0; i < 3; i++){
    uint2 vr = *(const uint2*)&pr[lane * 2 + i * 128];
    float4 av = *(const float4*)&att[(lane + i * 64) * 4];
    xrv[i*4+0] = bf2f(vr.x); xrv[i*4+1] = bf2f(vr.x >> 16);
    xrv[i*4+2] = bf2f(vr.y); xrv[i*4+3] = bf2f(vr.y >> 16);
    attv[i*4+0] = av.x; attv[i*4+1] = av.y; attv[i*4+2] = av.z; attv[i*4+3] = av.w;
  }
  float m = -INFINITY, den = 0.f, acc[12];
#pragma unroll
  for (int t = 0; t < 12; t++) acc[t] = 0.f;
  int j0 = off[d], j1 = off[d + 1];
  for (int j = j0; j < j1; j++){
    int k = csr[j], s = e_src(ep, E0, k);
    const unsigned* pl = (const unsigned*)(xl + (size_t)s * H);
    float xv[12];
#pragma unroll
    for (int i = 0; i < 3; i++){
      uint2 vl = *(const uint2*)&pl[lane * 2 + i * 128];
      xv[i*4+0] = bf2f(vl.x); xv[i*4+1] = bf2f(vl.x >> 16);
      xv[i*4+2] = bf2f(vl.y); xv[i*4+3] = bf2f(vl.y >> 16);
    }
    float p = 0.f;
#pragma unroll
    for (int t = 0; t < 12; t++){
      float v = xv[t] + xrv[t];
      v = (v > 0.f) ? v : 0.2f * v;
      p += v * attv[t];
    }
    p = wave_sum(p);
    float mn = fmaxf(m, p);
    float sc = __expf(m - mn), wgt = __expf(p - mn);
    den = den * sc + wgt;
#pragma unroll
    for (int t = 0; t < 12; t++) acc[t] = acc[t] * sc + wgt * xv[t];
    m = mn;
  }
  float inv = 1.0f / den;
  float y[12];
  float s1 = 0.f;
#pragma unroll
  for (int i = 0; i < 3; i++){
    float4 bv = *(const float4*)&bias[(lane + i * 64) * 4];
    y[i*4+0] = acc[i*4+0] * inv + bv.x;
    y[i*4+1] = acc[i*4+1] * inv + bv.y;
    y[i*4+2] = acc[i*4+2] * inv + bv.z;
    y[i*4+3] = acc[i*4+3] * inv + bv.w;
  }
#pragma unroll
  for (int t = 0; t < 12; t++) s1 += y[t];
  float mean = wave_sum(s1) * (1.0f / H);
  float s2 = 0.f;
#pragma unroll
  for (int t = 0; t < 12; t++){ float dt = y[t] - mean; s2 += dt * dt; }
  float rstd = rsqrtf(wave_sum(s2) * (1.0f / H) + 1e-5f);
  OutT* op = out + (size_t)d * H;
#pragma unroll
  for (int i = 0; i < 3; i++){
    float4 gv = *(const float4*)&g[(lane + i * 64) * 4];
    float4 bv = *(const float4*)&b[(lane + i * 64) * 4];
    float z0 = gelu_exact((y[i*4+0] - mean) * rstd * gv.x + bv.x);
    float z1 = gelu_exact((y[i*4+1] - mean) * rstd * gv.y + bv.y);
    float z2 = gelu_exact((y[i*4+2] - mean) * rstd * gv.z + bv.z);
    float z3 = gelu_exact((y[i*4+3] - mean) * rstd * gv.w + bv.w);
    if constexpr (sizeof(OutT) == 2){
      uint2 pk; pk.x = f2bf2(z0, z1); pk.y = f2bf2(z2, z3);
      *(uint2*)((unsigned*)op + lane * 2 + i * 128) = pk;
    } else {
      float4 fv; fv.x = z0; fv.y = z1; fv.z = z2; fv.w = z3;
      *(float4*)&op[(lane + i * 64) * 4] = fv;
    }
  }
}

extern "C" void kernel_launch(void* const* d_in, const int* in_sizes, int n_in,
                              void* d_out, int out_size, void* d_ws, size_t ws_size,
                              hipStream_t stream){
  const float* emb   = (const float*)d_in[0];
  const float* feats = (const float*)d_in[1];
  const int*   edges = (const int*)d_in[2];
  const float* Wl2 = (const float*)d_in[4],  *bl2 = (const float*)d_in[5];
  const float* Wr2 = (const float*)d_in[6],  *br2 = (const float*)d_in[7];
  const float* att2= (const float*)d_in[8],  *bias2=(const float*)d_in[9];
  const float* Wl3 = (const float*)d_in[10], *bl3 = (const float*)d_in[11];
  const float* Wr3 = (const float*)d_in[12], *br3 = (const float*)d_in[13];
  const float* att3= (const float*)d_in[14], *bias3=(const float*)d_in[15];
  const float* g1 = (const float*)d_in[16], *b1 = (const float*)d_in[17];
  const float* g2 = (const float*)d_in[18], *b2 = (const float*)d_in[19];
  const float* g3 = (const float*)d_in[20], *b3 = (const float*)d_in[21];

  const int N  = in_sizes[1] / H;             // 50000
  const int E0 = in_sizes[2] / 2;             // 100000
  const int E  = E0 + N;                      // 150000
  const int L  = 4096;                        // labels_size
  const int panels256 = (N + 255) / 256;              // 196 (196*6 % 8 == 0)
  const int Mpad = panels256 * 256;                    // 50176 (= round-7 footprint)
  const int panels128 = Mpad / BM;                     // 392 (layer-2 kernel grid)
  const int nchunk = (N + 1023) / 1024;                // 49 (<= 64)

  __hip_bfloat16* ab  = (__hip_bfloat16*)d_ws;          // [Mpad][H] GEMM input
  __hip_bfloat16* xl  = ab + (size_t)Mpad * H;          // [Mpad][H]
  __hip_bfloat16* xr  = xl + (size_t)Mpad * H;          // [Mpad][H]
  __hip_bfloat16* wt2 = xr + (size_t)Mpad * H;          // [1536][H]
  __hip_bfloat16* wt3 = wt2 + (size_t)2 * H * H;        // [1536][H]
  int* cnt  = (int*)(wt3 + (size_t)2 * H * H);          // [N]
  int* flag = cnt + N;                                  // [N]
  int* off  = flag + N;                                 // [N+1]
  int* cur  = off + N + 1;                              // [N]
  int* csr  = cur + N;                                  // [E]
  int* sums = csr + E;                                  // [64]
  int* fpos = sums + 64;                                // [N+1]
  int* fsums= fpos + N + 1;                             // [64]
  int* list = fsums + 64;                               // [N]

  float* out_f = (float*)d_out;

  // output 0: passthrough copy of input_embeddings
  hipMemcpyAsync(out_f, emb, (size_t)in_sizes[0] * sizeof(float),
                 hipMemcpyDeviceToDevice, stream);

  // CSR by dst + layer-2 src flags (one pass over edges)
  hipMemsetAsync(cnt, 0, (size_t)2 * N * sizeof(int), stream);
  count_mark_kernel<<<(E + 255) / 256, 256, 0, stream>>>(edges, E0, E, L, cnt, flag);
  scan1_kernel<<<nchunk, 1024, 0, stream>>>(cnt, off, sums, N);
  scan2_kernel<<<1, 64, 0, stream>>>(sums, off, nchunk, N);
  scan3_kernel<<<nchunk, 1024, 0, stream>>>(off, cur, sums, N);
  fill_kernel<<<(E + 255) / 256, 256, 0, stream>>>(edges, E0, E, cur, csr);
  // ordered compaction of flagged src rows -> list, count in fpos[N]
  scan1_kernel<<<nchunk, 1024, 0, stream>>>(flag, fpos, fsums, N);
  scan2_kernel<<<1, 64, 0, stream>>>(fsums, fpos, nchunk, N);
  flist_kernel<<<nchunk, 1024, 0, stream>>>(flag, fpos, fsums, list, N);

  // weights -> bf16 transposed, concatenated [Wl^T ; Wr^T]
  dim3 wgrid(H / 32, H / 32);
  wt_bf16_kernel<<<wgrid, 256, 0, stream>>>(Wl2, wt2);
  wt_bf16_kernel<<<wgrid, 256, 0, stream>>>(Wr2, wt2 + (size_t)H * H);
  wt_bf16_kernel<<<wgrid, 256, 0, stream>>>(Wl3, wt3);
  wt_bf16_kernel<<<wgrid, 256, 0, stream>>>(Wr3, wt3 + (size_t)H * H);

  // ---- layer 1 (full N): 256x256 8-wave GEMM ----
  lnw_kernel<<<(N + 3) / 4, 256, 0, stream>>>(feats, g1, b1, ab, N);
  gemm256_kernel<<<panels256 * 6, 512, 0, stream>>>(ab, wt2, bl2, br2, xl, xr,
                                                    panels256, N);
  agat_kernel<__hip_bfloat16><<<(N + 3) / 4, 256, 0, stream>>>(
      xl, xr, att2, off, csr, edges, E0, bias2, g2, b2, ab, N);

  // ---- layer 2 (xl only for compacted src rows; xr + aggregation only rows < L) ----
  gemm_fused_kernel<<<panels128 * 12, 256, 0, stream>>>(ab, wt3, bl3, br3, xl, xr,
                                                        list, fpos + N, panels128, L);
  agat_kernel<float><<<(L + 3) / 4, 256, 0, stream>>>(
      xl, xr, att3, off, csr, edges, E0, bias3, g3, b3, out_f + in_sizes[0], L);
}

// Round 10
// 388.824 us; speedup vs baseline: 1.2693x; 1.0369x over previous
//
#include <hip/hip_runtime.h>
#include <hip/hip_bf16.h>
#include <math.h>

#define H 768
#define BM 128

typedef __attribute__((ext_vector_type(4))) float f32x4;
typedef __attribute__((ext_vector_type(8))) short bf16x8;

__device__ __forceinline__ float bf2f(unsigned u16v){
  return __uint_as_float((u16v & 0xffffu) << 16);
}
__device__ __forceinline__ unsigned f2bf2(float a, float b){
  __hip_bfloat16 ha = __float2bfloat16(a), hb = __float2bfloat16(b);
  return (unsigned)*(unsigned short*)&ha | ((unsigned)*(unsigned short*)&hb << 16);
}
__device__ __forceinline__ float gelu_exact(float x){
  return 0.5f * x * (1.0f + erff(x * 0.70710678118654752f));
}
__device__ __forceinline__ void gload16(const void* g, void* l){
  __builtin_amdgcn_global_load_lds(
      (const __attribute__((address_space(1))) unsigned int*)g,
      (__attribute__((address_space(3))) unsigned int*)l,
      16, 0, 0);
}
__device__ __forceinline__ float wave_sum(float p){
#pragma unroll
  for (int o = 32; o; o >>= 1) p += __shfl_xor(p, o);
  return p;
}

// ---------------- LayerNorm + exact GELU: one WAVE per row, f32 in, bf16 out ----------------
__global__ __launch_bounds__(256) void lnw_kernel(
    const float* __restrict__ in, const float* __restrict__ g,
    const float* __restrict__ b, __hip_bfloat16* __restrict__ out, int rows){
  int row = blockIdx.x * 4 + (threadIdx.x >> 6);
  if (row >= rows) return;
  int lane = threadIdx.x & 63;
  const float* rp = in + (size_t)row * H;
  float v[12];
#pragma unroll
  for (int i = 0; i < 3; i++){
    float4 t = *(const float4*)&rp[(lane + i * 64) * 4];
    v[i*4+0] = t.x; v[i*4+1] = t.y; v[i*4+2] = t.z; v[i*4+3] = t.w;
  }
  float s = 0.f;
#pragma unroll
  for (int t = 0; t < 12; t++) s += v[t];
  float mean = wave_sum(s) * (1.0f / H);
  float s2 = 0.f;
#pragma unroll
  for (int t = 0; t < 12; t++){ float d = v[t] - mean; s2 += d * d; }
  float rstd = rsqrtf(wave_sum(s2) * (1.0f / H) + 1e-5f);
  unsigned* op = (unsigned*)(out + (size_t)row * H);
#pragma unroll
  for (int i = 0; i < 3; i++){
    float4 gv = *(const float4*)&g[(lane + i * 64) * 4];
    float4 bv = *(const float4*)&b[(lane + i * 64) * 4];
    float z0 = gelu_exact((v[i*4+0] - mean) * rstd * gv.x + bv.x);
    float z1 = gelu_exact((v[i*4+1] - mean) * rstd * gv.y + bv.y);
    float z2 = gelu_exact((v[i*4+2] - mean) * rstd * gv.z + bv.z);
    float z3 = gelu_exact((v[i*4+3] - mean) * rstd * gv.w + bv.w);
    uint2 pk; pk.x = f2bf2(z0, z1); pk.y = f2bf2(z2, z3);
    *(uint2*)&op[lane * 2 + i * 128] = pk;
  }
}

// ---------------- weight transpose + f32->bf16: WT[n][k] = W[k][n] ----------------
__global__ __launch_bounds__(256) void wt_bf16_kernel(
    const float* __restrict__ W, __hip_bfloat16* __restrict__ WT){
  __shared__ float tile[32][33];
  int k0 = blockIdx.x * 32, n0 = blockIdx.y * 32;
  int tx = threadIdx.x & 31, ty = threadIdx.x >> 5;   // 32 x 8
#pragma unroll
  for (int i = 0; i < 32; i += 8)
    tile[ty + i][tx] = W[(size_t)(k0 + ty + i) * H + n0 + tx];
  __syncthreads();
#pragma unroll
  for (int i = 0; i < 32; i += 8)
    WT[(size_t)(n0 + ty + i) * H + k0 + tx] = __float2bfloat16(tile[tx][ty + i]);
}

// ---------------- 256x256 8-wave bf16 MFMA GEMM, 4-phase interleave (layer 1) ----------------
// [Cl | Cr] = A[196*256,768] @ WT[1536,768]^T (+bias). BK=64, 2x64KB dbuf,
// per-phase {ds_read || stage-issue -> barrier -> lgkmcnt(0) -> setprio(1) ->
// 16 MFMA -> setprio(0) -> barrier}; vmcnt(0) once per K-tile before buffer flip.
// Race-safety: stage writes to buf^1 issue only after the barrier following
// lgkmcnt(0)-drained reads of buf^1; staged data read only after vmcnt(0)+barrier.
__global__ __launch_bounds__(512, 2) void gemm256_kernel(
    const __hip_bfloat16* __restrict__ A,
    const __hip_bfloat16* __restrict__ WT,
    const float* __restrict__ bl, const float* __restrict__ br,
    __hip_bfloat16* __restrict__ Cl, __hip_bfloat16* __restrict__ Cr,
    int panels, int Nrows){
  __shared__ char smem[131072];         // 2 x 64KB pipeline; epilogue C: 128KB

  // bijective XCD-contiguous mapping: total blocks = panels*6 (divisible by 8)
  int spp = (panels * 6) >> 3;
  int s = (blockIdx.x & 7) * spp + (blockIdx.x >> 3);
  int panel = s / 6, colblk = s % 6;
  int row0 = panel * 256;
  const bool is_r = colblk >= 3;

  const int t = threadIdx.x;
  const int sr8 = t >> 3;                              // staging row in 64-row chunk
  const int sw8 = (((t & 7) ^ ((sr8 >> 1) & 7)) * 8);  // pre-swizzled global col (elems)
  const int t16 = t * 16;
  int raw0 = min(row0 + sr8,       Nrows - 1);
  int raw1 = min(row0 + 64  + sr8, Nrows - 1);
  int raw2 = min(row0 + 128 + sr8, Nrows - 1);
  int raw3 = min(row0 + 192 + sr8, Nrows - 1);
  const __hip_bfloat16* pA0 = A + (size_t)raw0 * H + sw8;
  const __hip_bfloat16* pA1 = A + (size_t)raw1 * H + sw8;
  const __hip_bfloat16* pA2 = A + (size_t)raw2 * H + sw8;
  const __hip_bfloat16* pA3 = A + (size_t)raw3 * H + sw8;
  const __hip_bfloat16* pB0 = WT + (size_t)(colblk * 256 +       sr8) * H + sw8;
  const __hip_bfloat16* pB1 = WT + (size_t)(colblk * 256 + 64  + sr8) * H + sw8;
  const __hip_bfloat16* pB2 = WT + (size_t)(colblk * 256 + 128 + sr8) * H + sw8;
  const __hip_bfloat16* pB3 = WT + (size_t)(colblk * 256 + 192 + sr8) * H + sw8;

  const int l = t & 63, w = t >> 6;
  const int wr = w >> 2, wc = w & 3;                   // 2 x 4 waves, 128x64 per wave
  const int r0 = l & 15;
  const int swz = (r0 >> 1) & 7;
  const int kb0 = (((l >> 4)    ) ^ swz) * 16;         // ks=0 swizzled byte col
  const int kb1 = (((l >> 4) + 4) ^ swz) * 16;         // ks=1 (kq+4 ^ swz)

  f32x4 acc[8][4];
#pragma unroll
  for (int m = 0; m < 8; m++)
#pragma unroll
    for (int n = 0; n < 4; n++) acc[m][n] = (f32x4){0.f, 0.f, 0.f, 0.f};
  bf16x8 af[4][2], bfr[2][2][2];

#define STAGE_A(koE, BB) do{ char* _d = smem + (BB) * 65536;          \
    gload16(pA0 + (koE), _d + t16);                                    \
    gload16(pA1 + (koE), _d + 8192 + t16);                             \
    gload16(pA2 + (koE), _d + 16384 + t16);                            \
    gload16(pA3 + (koE), _d + 24576 + t16); }while(0)
#define STAGE_B(koE, BB) do{ char* _d = smem + (BB) * 65536 + 32768;  \
    gload16(pB0 + (koE), _d + t16);                                    \
    gload16(pB1 + (koE), _d + 8192 + t16);                             \
    gload16(pB2 + (koE), _d + 16384 + t16);                            \
    gload16(pB3 + (koE), _d + 24576 + t16); }while(0)
#define LOAD_AF(MH) do{ const char* _b = bb + (wr * 2 + (MH)) * 8192; \
    _Pragma("unroll") for (int i = 0; i < 4; i++){                     \
      const char* _r = _b + (i * 16 + r0) * 128;                       \
      af[i][0] = *(const bf16x8*)(_r + kb0);                           \
      af[i][1] = *(const bf16x8*)(_r + kb1); } }while(0)
#define LOAD_BF(NH) do{ const char* _b = bb + 32768 + wc * 8192 + ((NH) * 32 + r0) * 128; \
    _Pragma("unroll") for (int j = 0; j < 2; j++){                     \
      const char* _r = _b + j * 2048;                                  \
      bfr[NH][j][0] = *(const bf16x8*)(_r + kb0);                      \
      bfr[NH][j][1] = *(const bf16x8*)(_r + kb1); } }while(0)
#define MFMA_Q(MH, NH)                                                 \
    _Pragma("unroll") for (int i = 0; i < 4; i++)                      \
      _Pragma("unroll") for (int j = 0; j < 2; j++)                    \
        _Pragma("unroll") for (int ks = 0; ks < 2; ks++)               \
          acc[(MH)*4+i][(NH)*2+j] = __builtin_amdgcn_mfma_f32_16x16x32_bf16( \
              af[i][ks], bfr[NH][j][ks], acc[(MH)*4+i][(NH)*2+j], 0, 0, 0);
#define PH_SYNC do{ __builtin_amdgcn_s_barrier();                      \
    asm volatile("s_waitcnt lgkmcnt(0)" ::: "memory");                 \
    __builtin_amdgcn_sched_barrier(0); }while(0)

  // prologue: stage K-tile 0 into buffer 0, drain, sync
  STAGE_A(0, 0); STAGE_B(0, 0);
  asm volatile("s_waitcnt vmcnt(0)" ::: "memory");
  __builtin_amdgcn_s_barrier();

  for (int kt = 0; kt < 12; kt++){
    const char* bb = smem + (kt & 1) * 65536;
    const int nb = (kt & 1) ^ 1;
    const bool st = kt < 11;
    const int ko = (kt + 1) * 64;
    // P0: read af(mh0) + both bfr halves; stage A of next tile
    LOAD_AF(0); LOAD_BF(0); LOAD_BF(1);
    if (st) STAGE_A(ko, nb);
    PH_SYNC;
    __builtin_amdgcn_s_setprio(1); MFMA_Q(0, 0); __builtin_amdgcn_s_setprio(0);
    __builtin_amdgcn_s_barrier();
    // P1: stage B of next tile
    if (st) STAGE_B(ko, nb);
    PH_SYNC;
    __builtin_amdgcn_s_setprio(1); MFMA_Q(0, 1); __builtin_amdgcn_s_setprio(0);
    __builtin_amdgcn_s_barrier();
    // P2: read af(mh1)
    LOAD_AF(1);
    PH_SYNC;
    __builtin_amdgcn_s_setprio(1); MFMA_Q(1, 1); __builtin_amdgcn_s_setprio(0);
    __builtin_amdgcn_s_barrier();
    // P3: pure MFMA; drain next tile's stage before buffer flip
    PH_SYNC;
    __builtin_amdgcn_s_setprio(1); MFMA_Q(1, 0); __builtin_amdgcn_s_setprio(0);
    asm volatile("s_waitcnt vmcnt(0)" ::: "memory");
    __builtin_amdgcn_s_barrier();
  }
#undef STAGE_A
#undef STAGE_B
#undef LOAD_AF
#undef LOAD_BF
#undef MFMA_Q
#undef PH_SYNC

  // epilogue: stage C (256 x 512B rows) in LDS with 32B-chunk XOR, 16B stores
  __syncthreads();
  const int rgrp = (l >> 4) * 4;
  const int colblk2 = is_r ? colblk - 3 : colblk;
  const float* bp = is_r ? br : bl;
  const int cb = colblk2 * 256;
#pragma unroll
  for (int n = 0; n < 4; n++){
    int lc = wc * 64 + n * 16 + r0;
    float bb2 = bp[cb + lc];
#pragma unroll
    for (int m = 0; m < 8; m++){
#pragma unroll
      for (int jj = 0; jj < 4; jj++){
        int lr = wr * 128 + m * 16 + rgrp + jj;
        int byte = lr * 512 + ((lc * 2) ^ (((lr >> 2) & 3) << 5));
        *(__hip_bfloat16*)(smem + byte) = __float2bfloat16(acc[m][n][jj] + bb2);
      }
    }
  }
  __syncthreads();
  __hip_bfloat16* C = is_r ? Cr : Cl;
#pragma unroll
  for (int p = 0; p < 16; p++){
    int ba = p * 8192 + t16;
    int lr = ba >> 9, inner = ba & 511;
    uint4 v = *(const uint4*)(smem + lr * 512 + (inner ^ (((lr >> 2) & 3) << 5)));
    *(uint4*)(C + (size_t)(row0 + lr) * H + cb + (inner >> 1)) = v;
  }
}

// ---------------- 128x128 4-wave GEMM with row-compaction (layer 2) ----------------
__global__ __launch_bounds__(256, 3) void gemm_fused_kernel(
    const __hip_bfloat16* __restrict__ A,
    const __hip_bfloat16* __restrict__ WT,
    const float* __restrict__ bl, const float* __restrict__ br,
    __hip_bfloat16* __restrict__ Cl, __hip_bfloat16* __restrict__ Cr,
    const int* __restrict__ rmap, const int* __restrict__ nr_p,
    int panels, int Mr){
  __shared__ char smem[49152];          // 3 x (As 8KB | Bs 8KB)

  int wgid = blockIdx.x;
  int panel = wgid / 12, colblk = wgid % 12;   // identity: spreads active blocks
  int row0 = panel * BM;
  const bool is_r = colblk >= 6;
  int nrl = *nr_p;
  if (is_r){ if (row0 >= Mr) return; }
  else     { if (row0 >= nrl) return; }
  const bool remap = !is_r;

  const int t = threadIdx.x;
  const int sr = t >> 2;
  const int scs = (((t & 3) ^ ((sr >> 1) & 3)) * 8);
  const int t16 = t * 16;
  int ra0 = row0 + sr, ra1 = row0 + sr + 64;
  if (remap){
    ra0 = rmap[min(ra0, nrl - 1)];
    ra1 = rmap[min(ra1, nrl - 1)];
  }
  const __hip_bfloat16* pa0 = A + (size_t)ra0 * H + scs;
  const __hip_bfloat16* pa1 = A + (size_t)ra1 * H + scs;
  const __hip_bfloat16* pb0 = WT + (size_t)(colblk * 128 + sr) * H + scs;
  const __hip_bfloat16* pb1 = pb0 + (size_t)64 * H;

  const int l = t & 63, w = t >> 6;
  const int wm = (w >> 1) * 64, wn = (w & 1) * 64;
  const int r0 = l & 15;
  const int kcs2 = (((l >> 4) ^ ((r0 >> 1) & 3)) * 16);

  f32x4 acc[4][4];
#pragma unroll
  for (int m = 0; m < 4; m++)
#pragma unroll
    for (int n = 0; n < 4; n++) acc[m][n] = (f32x4){0.f, 0.f, 0.f, 0.f};

#define STAGE(kt, b) do{                                   \
    int _k0 = (kt) * 32;                                   \
    char* _bs = smem + (b) * 16384;                        \
    gload16(pa0 + _k0, _bs + t16);                         \
    gload16(pa1 + _k0, _bs + 4096 + t16);                  \
    gload16(pb0 + _k0, _bs + 8192 + t16);                  \
    gload16(pb1 + _k0, _bs + 12288 + t16);                 \
  }while(0)

  STAGE(0, 0);
  STAGE(1, 1);

  for (int kt = 0; kt < 24; kt++){
    if (kt < 23) asm volatile("s_waitcnt vmcnt(4)" ::: "memory");
    else         asm volatile("s_waitcnt vmcnt(0)" ::: "memory");
    __builtin_amdgcn_s_barrier();
    __builtin_amdgcn_sched_barrier(0);
    if (kt + 2 < 24) STAGE(kt + 2, (kt + 2) % 3);
    const char* base = smem + (kt % 3) * 16384;
    bf16x8 af[4], bfr[4];
#pragma unroll
    for (int m = 0; m < 4; m++)
      af[m]  = *(const bf16x8*)(base + (wm + m * 16 + r0) * 64 + kcs2);
#pragma unroll
    for (int n = 0; n < 4; n++)
      bfr[n] = *(const bf16x8*)(base + 8192 + (wn + n * 16 + r0) * 64 + kcs2);
#pragma unroll
    for (int m = 0; m < 4; m++)
#pragma unroll
      for (int n = 0; n < 4; n++)
        acc[m][n] = __builtin_amdgcn_mfma_f32_16x16x32_bf16(af[m], bfr[n], acc[m][n], 0, 0, 0);
  }
#undef STAGE

  __syncthreads();
  const int rgrp = (l >> 4) * 4;
  const float* bp = is_r ? br : bl;
  const int cb = (is_r ? colblk - 6 : colblk) * 128;
#pragma unroll
  for (int n = 0; n < 4; n++){
    int lc = wn + n * 16 + r0;
    float bb = bp[cb + lc];
#pragma unroll
    for (int m = 0; m < 4; m++){
#pragma unroll
      for (int jj = 0; jj < 4; jj++){
        int lr = wm + m * 16 + rgrp + jj;
        int byte = lr * 256 + ((lc * 2) ^ (((lr >> 2) & 3) << 5));
        *(__hip_bfloat16*)(smem + byte) = __float2bfloat16(acc[m][n][jj] + bb);
      }
    }
  }
  __syncthreads();
  __hip_bfloat16* C = is_r ? Cr : Cl;
#pragma unroll
  for (int p = 0; p < 8; p++){
    int ba = p * 4096 + t16;
    int lr = ba >> 8, inner = ba & 255;
    int gr = row0 + lr;
    if (!is_r && gr >= nrl) continue;
    int orow = remap ? rmap[gr] : gr;
    uint4 v = *(const uint4*)(smem + lr * 256 + (inner ^ (((lr >> 2) & 3) << 5)));
    *(uint4*)(C + (size_t)orow * H + cb + (inner >> 1)) = v;
  }
}

// ---------------- edge helpers ----------------
__device__ __forceinline__ int e_src(const int* ep, int E0, int k){
  return (k < E0) ? ep[k] : (k - E0);
}
__device__ __forceinline__ int e_dst(const int* ep, int E0, int k){
  return (k < E0) ? ep[E0 + k] : (k - E0);
}

// ---------------- CSR build + layer-2 src marking (fused) ----------------
__global__ __launch_bounds__(256) void count_mark_kernel(const int* __restrict__ ep,
                                                         int E0, int E, int L,
                                                         int* __restrict__ cnt,
                                                         int* __restrict__ flag){
  int k = blockIdx.x * 256 + threadIdx.x;
  if (k >= E) return;
  int d = e_dst(ep, E0, k);
  atomicAdd(&cnt[d], 1);
  if (d < L) flag[e_src(ep, E0, k)] = 1;       // benign same-value race
}

__global__ __launch_bounds__(1024) void scan1_kernel(const int* __restrict__ cnt,
                                                     int* __restrict__ off,
                                                     int* __restrict__ sums, int n){
  __shared__ int lds[1024];
  int tid = threadIdx.x;
  int gi = blockIdx.x * 1024 + tid;
  int v = (gi < n) ? cnt[gi] : 0;
  lds[tid] = v;
  __syncthreads();
  for (int o = 1; o < 1024; o <<= 1){
    int tv = (tid >= o) ? lds[tid - o] : 0;
    __syncthreads();
    lds[tid] += tv;
    __syncthreads();
  }
  if (gi < n) off[gi] = lds[tid] - v;
  if (tid == 1023) sums[blockIdx.x] = lds[1023];
}

__global__ void scan2_kernel(int* __restrict__ sums, int* __restrict__ off,
                             int nb, int n){
  int lane = threadIdx.x;                      // single wave of 64, nb <= 64
  int v = (lane < nb) ? sums[lane] : 0;
  int incl = v;
#pragma unroll
  for (int o = 1; o < 64; o <<= 1){
    int t = __shfl_up(incl, o);
    if (lane >= o) incl += t;
  }
  if (lane < nb) sums[lane] = incl - v;
  if (lane == nb - 1) off[n] = incl;
}

__global__ __launch_bounds__(1024) void scan3_kernel(int* __restrict__ off,
                                                     int* __restrict__ cur,
                                                     const int* __restrict__ sums, int n){
  int gi = blockIdx.x * 1024 + threadIdx.x;
  if (gi < n){
    int v = off[gi] + sums[blockIdx.x];
    off[gi] = v;
    cur[gi] = v;
  }
}

__global__ __launch_bounds__(1024) void flist_kernel(const int* __restrict__ flag,
                                                     const int* __restrict__ fpos,
                                                     const int* __restrict__ fsums,
                                                     int* __restrict__ list, int n){
  int gi = blockIdx.x * 1024 + threadIdx.x;
  if (gi < n && flag[gi]) list[fpos[gi] + fsums[blockIdx.x]] = gi;
}

__global__ __launch_bounds__(256) void fill_kernel(const int* __restrict__ ep, int E0, int E,
                                                   int* __restrict__ cur, int* __restrict__ csr){
  int k = blockIdx.x * 256 + threadIdx.x;
  if (k >= E) return;
  int d = e_dst(ep, E0, k);
  int pos = atomicAdd(&cur[d], 1);
  csr[pos] = k;
}

// ---------------- fused GAT attend+aggregate+LN+GELU: one WAVE per dst ----------------
template<typename OutT>
__global__ __launch_bounds__(256) void agat_kernel(
    const __hip_bfloat16* __restrict__ xl, const __hip_bfloat16* __restrict__ xr,
    const float* __restrict__ att, const int* __restrict__ off,
    const int* __restrict__ csr, const int* __restrict__ ep, int E0,
    const float* __restrict__ bias, const float* __restrict__ g,
    const float* __restrict__ b, OutT* __restrict__ out, int ndst){
  int d = blockIdx.x * 4 + (threadIdx.x >> 6);
  if (d >= ndst) return;
  int lane = threadIdx.x & 63;
  float xrv[12], attv[12];
  const unsigned* pr = (const unsigned*)(xr + (size_t)d * H);
#pragma unroll
  for (int i = 0; i < 3; i++){
    uint2 vr = *(const uint2*)&pr[lane * 2 + i * 128];
    float4 av = *(const float4*)&att[(lane + i * 64) * 4];
    xrv[i*4+0] = bf2f(vr.x); xrv[i*4+1] = bf2f(vr.x >> 16);
    xrv[i*4+2] = bf2f(vr.y); xrv[i*4+3] = bf2f(vr.y >> 16);
    attv[i*4+0] = av.x; attv[i*4+1] = av.y; attv[i*4+2] = av.z; attv[i*4+3] = av.w;
  }
  float m = -INFINITY, den = 0.f, acc[12];
#pragma unroll
  for (int t = 0; t < 12; t++) acc[t] = 0.f;
  int j0 = off[d], j1 = off[d + 1];
  for (int j = j0; j < j1; j++){
    int k = csr[j], s = e_src(ep, E0, k);
    const unsigned* pl = (const unsigned*)(xl + (size_t)s * H);
    float xv[12];
#pragma unroll
    for (int i = 0; i < 3; i++){
      uint2 vl = *(const uint2*)&pl[lane * 2 + i * 128];
      xv[i*4+0] = bf2f(vl.x); xv[i*4+1] = bf2f(vl.x >> 16);
      xv[i*4+2] = bf2f(vl.y); xv[i*4+3] = bf2f(vl.y >> 16);
    }
    float p = 0.f;
#pragma unroll
    for (int t = 0; t < 12; t++){
      float v = xv[t] + xrv[t];
      v = (v > 0.f) ? v : 0.2f * v;
      p += v * attv[t];
    }
    p = wave_sum(p);
    float mn = fmaxf(m, p);
    float sc = __expf(m - mn), wgt = __expf(p - mn);
    den = den * sc + wgt;
#pragma unroll
    for (int t = 0; t < 12; t++) acc[t] = acc[t] * sc + wgt * xv[t];
    m = mn;
  }
  float inv = 1.0f / den;
  float y[12];
  float s1 = 0.f;
#pragma unroll
  for (int i = 0; i < 3; i++){
    float4 bv = *(const float4*)&bias[(lane + i * 64) * 4];
    y[i*4+0] = acc[i*4+0] * inv + bv.x;
    y[i*4+1] = acc[i*4+1] * inv + bv.y;
    y[i*4+2] = acc[i*4+2] * inv + bv.z;
    y[i*4+3] = acc[i*4+3] * inv + bv.w;
  }
#pragma unroll
  for (int t = 0; t < 12; t++) s1 += y[t];
  float mean = wave_sum(s1) * (1.0f / H);
  float s2 = 0.f;
#pragma unroll
  for (int t = 0; t < 12; t++){ float dt = y[t] - mean; s2 += dt * dt; }
  float rstd = rsqrtf(wave_sum(s2) * (1.0f / H) + 1e-5f);
  OutT* op = out + (size_t)d * H;
#pragma unroll
  for (int i = 0; i < 3; i++){
    float4 gv = *(const float4*)&g[(lane + i * 64) * 4];
    float4 bv = *(const float4*)&b[(lane + i * 64) * 4];
    float z0 = gelu_exact((y[i*4+0] - mean) * rstd * gv.x + bv.x);
    float z1 = gelu_exact((y[i*4+1] - mean) * rstd * gv.y + bv.y);
    float z2 = gelu_exact((y[i*4+2] - mean) * rstd * gv.z + bv.z);
    float z3 = gelu_exact((y[i*4+3] - mean) * rstd * gv.w + bv.w);
    if constexpr (sizeof(OutT) == 2){
      uint2 pk; pk.x = f2bf2(z0, z1); pk.y = f2bf2(z2, z3);
      *(uint2*)((unsigned*)op + lane * 2 + i * 128) = pk;
    } else {
      float4 fv; fv.x = z0; fv.y = z1; fv.z = z2; fv.w = z3;
      *(float4*)&op[(lane + i * 64) * 4] = fv;
    }
  }
}

extern "C" void kernel_launch(void* const* d_in, const int* in_sizes, int n_in,
                              void* d_out, int out_size, void* d_ws, size_t ws_size,
                              hipStream_t stream){
  const float* emb   = (const float*)d_in[0];
  const float* feats = (const float*)d_in[1];
  const int*   edges = (const int*)d_in[2];
  const float* Wl2 = (const float*)d_in[4],  *bl2 = (const float*)d_in[5];
  const float* Wr2 = (const float*)d_in[6],  *br2 = (const float*)d_in[7];
  const float* att2= (const float*)d_in[8],  *bias2=(const float*)d_in[9];
  const float* Wl3 = (const float*)d_in[10], *bl3 = (const float*)d_in[11];
  const float* Wr3 = (const float*)d_in[12], *br3 = (const float*)d_in[13];
  const float* att3= (const float*)d_in[14], *bias3=(const float*)d_in[15];
  const float* g1 = (const float*)d_in[16], *b1 = (const float*)d_in[17];
  const float* g2 = (const float*)d_in[18], *b2 = (const float*)d_in[19];
  const float* g3 = (const float*)d_in[20], *b3 = (const float*)d_in[21];

  const int N  = in_sizes[1] / H;             // 50000
  const int E0 = in_sizes[2] / 2;             // 100000
  const int E  = E0 + N;                      // 150000
  const int L  = 4096;                        // labels_size
  const int panels256 = (N + 255) / 256;              // 196 (196*6 % 8 == 0)
  const int Mpad = panels256 * 256;                    // 50176
  const int panels128 = Mpad / BM;                     // 392
  const int nchunk = (N + 1023) / 1024;                // 49 (<= 64)

  __hip_bfloat16* ab  = (__hip_bfloat16*)d_ws;          // [Mpad][H] GEMM input
  __hip_bfloat16* xl  = ab + (size_t)Mpad * H;          // [Mpad][H]
  __hip_bfloat16* xr  = xl + (size_t)Mpad * H;          // [Mpad][H]
  __hip_bfloat16* wt2 = xr + (size_t)Mpad * H;          // [1536][H]
  __hip_bfloat16* wt3 = wt2 + (size_t)2 * H * H;        // [1536][H]
  int* cnt  = (int*)(wt3 + (size_t)2 * H * H);          // [N]
  int* flag = cnt + N;                                  // [N]
  int* off  = flag + N;                                 // [N+1]
  int* cur  = off + N + 1;                              // [N]
  int* csr  = cur + N;                                  // [E]
  int* sums = csr + E;                                  // [64]
  int* fpos = sums + 64;                                // [N+1]
  int* fsums= fpos + N + 1;                             // [64]
  int* list = fsums + 64;                               // [N]

  float* out_f = (float*)d_out;

  // output 0: passthrough copy of input_embeddings
  hipMemcpyAsync(out_f, emb, (size_t)in_sizes[0] * sizeof(float),
                 hipMemcpyDeviceToDevice, stream);

  // CSR by dst + layer-2 src flags (one pass over edges)
  hipMemsetAsync(cnt, 0, (size_t)2 * N * sizeof(int), stream);
  count_mark_kernel<<<(E + 255) / 256, 256, 0, stream>>>(edges, E0, E, L, cnt, flag);
  scan1_kernel<<<nchunk, 1024, 0, stream>>>(cnt, off, sums, N);
  scan2_kernel<<<1, 64, 0, stream>>>(sums, off, nchunk, N);
  scan3_kernel<<<nchunk, 1024, 0, stream>>>(off, cur, sums, N);
  fill_kernel<<<(E + 255) / 256, 256, 0, stream>>>(edges, E0, E, cur, csr);
  // ordered compaction of flagged src rows -> list, count in fpos[N]
  scan1_kernel<<<nchunk, 1024, 0, stream>>>(flag, fpos, fsums, N);
  scan2_kernel<<<1, 64, 0, stream>>>(fsums, fpos, nchunk, N);
  flist_kernel<<<nchunk, 1024, 0, stream>>>(flag, fpos, fsums, list, N);

  // weights -> bf16 transposed, concatenated [Wl^T ; Wr^T]
  dim3 wgrid(H / 32, H / 32);
  wt_bf16_kernel<<<wgrid, 256, 0, stream>>>(Wl2, wt2);
  wt_bf16_kernel<<<wgrid, 256, 0, stream>>>(Wr2, wt2 + (size_t)H * H);
  wt_bf16_kernel<<<wgrid, 256, 0, stream>>>(Wl3, wt3);
  wt_bf16_kernel<<<wgrid, 256, 0, stream>>>(Wr3, wt3 + (size_t)H * H);

  // ---- layer 1 (full N): 256x256 8-wave 4-phase GEMM ----
  lnw_kernel<<<(N + 3) / 4, 256, 0, stream>>>(feats, g1, b1, ab, N);
  gemm256_kernel<<<panels256 * 6, 512, 0, stream>>>(ab, wt2, bl2, br2, xl, xr,
                                                    panels256, N);
  agat_kernel<__hip_bfloat16><<<(N + 3) / 4, 256, 0, stream>>>(
      xl, xr, att2, off, csr, edges, E0, bias2, g2, b2, ab, N);

  // ---- layer 2 (xl only for compacted src rows; xr + aggregation only rows < L) ----
  gemm_fused_kernel<<<panels128 * 12, 256, 0, stream>>>(ab, wt3, bl3, br3, xl, xr,
                                                        list, fpos + N, panels128, L);
  agat_kernel<float><<<(L + 3) / 4, 256, 0, stream>>>(
      xl, xr, att3, off, csr, edges, E0, bias3, g3, b3, out_f + in_sizes[0], L);
}

// Round 11
// 381.244 us; speedup vs baseline: 1.2945x; 1.0199x over previous
//
#include <hip/hip_runtime.h>
#include <hip/hip_bf16.h>
#include <math.h>

#define H 768
#define BM 128

typedef __attribute__((ext_vector_type(4))) float f32x4;
typedef __attribute__((ext_vector_type(16))) float f32x16;
typedef __attribute__((ext_vector_type(8))) short bf16x8;

__device__ __forceinline__ float bf2f(unsigned u16v){
  return __uint_as_float((u16v & 0xffffu) << 16);
}
__device__ __forceinline__ unsigned f2bf2(float a, float b){
  __hip_bfloat16 ha = __float2bfloat16(a), hb = __float2bfloat16(b);
  return (unsigned)*(unsigned short*)&ha | ((unsigned)*(unsigned short*)&hb << 16);
}
__device__ __forceinline__ float gelu_exact(float x){
  return 0.5f * x * (1.0f + erff(x * 0.70710678118654752f));
}
__device__ __forceinline__ void gload16(const void* g, void* l){
  __builtin_amdgcn_global_load_lds(
      (const __attribute__((address_space(1))) unsigned int*)g,
      (__attribute__((address_space(3))) unsigned int*)l,
      16, 0, 0);
}
__device__ __forceinline__ float wave_sum(float p){
#pragma unroll
  for (int o = 32; o; o >>= 1) p += __shfl_xor(p, o);
  return p;
}

// ---------------- LayerNorm + exact GELU: one WAVE per row, f32 in, bf16 out ----------------
__global__ __launch_bounds__(256) void lnw_kernel(
    const float* __restrict__ in, const float* __restrict__ g,
    const float* __restrict__ b, __hip_bfloat16* __restrict__ out, int rows){
  int row = blockIdx.x * 4 + (threadIdx.x >> 6);
  if (row >= rows) return;
  int lane = threadIdx.x & 63;
  const float* rp = in + (size_t)row * H;
  float v[12];
#pragma unroll
  for (int i = 0; i < 3; i++){
    float4 t = *(const float4*)&rp[(lane + i * 64) * 4];
    v[i*4+0] = t.x; v[i*4+1] = t.y; v[i*4+2] = t.z; v[i*4+3] = t.w;
  }
  float s = 0.f;
#pragma unroll
  for (int t = 0; t < 12; t++) s += v[t];
  float mean = wave_sum(s) * (1.0f / H);
  float s2 = 0.f;
#pragma unroll
  for (int t = 0; t < 12; t++){ float d = v[t] - mean; s2 += d * d; }
  float rstd = rsqrtf(wave_sum(s2) * (1.0f / H) + 1e-5f);
  unsigned* op = (unsigned*)(out + (size_t)row * H);
#pragma unroll
  for (int i = 0; i < 3; i++){
    float4 gv = *(const float4*)&g[(lane + i * 64) * 4];
    float4 bv = *(const float4*)&b[(lane + i * 64) * 4];
    float z0 = gelu_exact((v[i*4+0] - mean) * rstd * gv.x + bv.x);
    float z1 = gelu_exact((v[i*4+1] - mean) * rstd * gv.y + bv.y);
    float z2 = gelu_exact((v[i*4+2] - mean) * rstd * gv.z + bv.z);
    float z3 = gelu_exact((v[i*4+3] - mean) * rstd * gv.w + bv.w);
    uint2 pk; pk.x = f2bf2(z0, z1); pk.y = f2bf2(z2, z3);
    *(uint2*)&op[lane * 2 + i * 128] = pk;
  }
}

// ---------------- weight transpose + f32->bf16 (all 4 matrices, z-indexed) ----------------
__global__ __launch_bounds__(256) void wt_bf16_kernel(
    const float* __restrict__ W0, const float* __restrict__ W1,
    const float* __restrict__ W2, const float* __restrict__ W3,
    __hip_bfloat16* __restrict__ T0, __hip_bfloat16* __restrict__ T1,
    __hip_bfloat16* __restrict__ T2, __hip_bfloat16* __restrict__ T3){
  int z = blockIdx.z;
  const float* W = (z == 0) ? W0 : (z == 1) ? W1 : (z == 2) ? W2 : W3;
  __hip_bfloat16* WT = (z == 0) ? T0 : (z == 1) ? T1 : (z == 2) ? T2 : T3;
  __shared__ float tile[32][33];
  int k0 = blockIdx.x * 32, n0 = blockIdx.y * 32;
  int tx = threadIdx.x & 31, ty = threadIdx.x >> 5;   // 32 x 8
#pragma unroll
  for (int i = 0; i < 32; i += 8)
    tile[ty + i][tx] = W[(size_t)(k0 + ty + i) * H + n0 + tx];
  __syncthreads();
#pragma unroll
  for (int i = 0; i < 32; i += 8)
    WT[(size_t)(n0 + ty + i) * H + k0 + tx] = __float2bfloat16(tile[tx][ty + i]);
}

// ---------------- 256x256 8-wave 32x32x16-MFMA GEMM, 4-phase interleave (layer 1) ----------------
// Same validated sync structure as round-10 (barriers/waits identical); only the
// fragment maps changed to mfma_f32_32x32x16_bf16 (half the MFMA instructions,
// higher measured ceiling). A/B lane map: row=l&31, k=(l>>5)*8+i.
// C/D map (HW-verified m74/m101): col=lane&31, row=(reg&3)+8*(reg>>2)+4*(lane>>5).
__global__ __launch_bounds__(512, 2) void gemm256_kernel(
    const __hip_bfloat16* __restrict__ A,
    const __hip_bfloat16* __restrict__ WT,
    const float* __restrict__ bl, const float* __restrict__ br,
    __hip_bfloat16* __restrict__ Cl, __hip_bfloat16* __restrict__ Cr,
    int panels, int Nrows){
  __shared__ char smem[131072];         // 2 x 64KB pipeline; epilogue C: 128KB

  int spp = (panels * 6) >> 3;          // bijective XCD-contiguous mapping
  int s = (blockIdx.x & 7) * spp + (blockIdx.x >> 3);
  int panel = s / 6, colblk = s % 6;
  int row0 = panel * 256;
  const bool is_r = colblk >= 3;

  const int t = threadIdx.x;
  const int sr8 = t >> 3;                              // staging row in 64-row chunk
  const int sw8 = (((t & 7) ^ ((sr8 >> 1) & 7)) * 8);  // pre-swizzled global col (elems)
  const int t16 = t * 16;
  int raw0 = min(row0 + sr8,       Nrows - 1);
  int raw1 = min(row0 + 64  + sr8, Nrows - 1);
  int raw2 = min(row0 + 128 + sr8, Nrows - 1);
  int raw3 = min(row0 + 192 + sr8, Nrows - 1);
  const __hip_bfloat16* pA0 = A + (size_t)raw0 * H + sw8;
  const __hip_bfloat16* pA1 = A + (size_t)raw1 * H + sw8;
  const __hip_bfloat16* pA2 = A + (size_t)raw2 * H + sw8;
  const __hip_bfloat16* pA3 = A + (size_t)raw3 * H + sw8;
  const __hip_bfloat16* pB0 = WT + (size_t)(colblk * 256 +       sr8) * H + sw8;
  const __hip_bfloat16* pB1 = WT + (size_t)(colblk * 256 + 64  + sr8) * H + sw8;
  const __hip_bfloat16* pB2 = WT + (size_t)(colblk * 256 + 128 + sr8) * H + sw8;
  const __hip_bfloat16* pB3 = WT + (size_t)(colblk * 256 + 192 + sr8) * H + sw8;

  const int l = t & 63, w = t >> 6;
  const int wr = w >> 2, wc = w & 3;                   // 2 x 4 waves, 128x64 per wave
  const int r31 = l & 31, kh = l >> 5;                 // A/B frag: row=l&31, k-half=l>>5
  const int swz = (r31 >> 1) & 7;
  int kbyte[4];
#pragma unroll
  for (int ks = 0; ks < 4; ks++) kbyte[ks] = ((ks * 2 + kh) ^ swz) * 16;

  f32x16 acc[4][2];
#pragma unroll
  for (int m = 0; m < 4; m++)
#pragma unroll
    for (int n = 0; n < 2; n++)
#pragma unroll
      for (int r = 0; r < 16; r++) acc[m][n][r] = 0.f;
  bf16x8 afr[4], bfr[2][4];

#define STAGE_A(koE, BB) do{ char* _d = smem + (BB) * 65536;          \
    gload16(pA0 + (koE), _d + t16);                                    \
    gload16(pA1 + (koE), _d + 8192 + t16);                             \
    gload16(pA2 + (koE), _d + 16384 + t16);                            \
    gload16(pA3 + (koE), _d + 24576 + t16); }while(0)
#define STAGE_B(koE, BB) do{ char* _d = smem + (BB) * 65536 + 32768;  \
    gload16(pB0 + (koE), _d + t16);                                    \
    gload16(pB1 + (koE), _d + 8192 + t16);                             \
    gload16(pB2 + (koE), _d + 16384 + t16);                            \
    gload16(pB3 + (koE), _d + 24576 + t16); }while(0)
#define LOAD_A(FM) do{                                                 \
    const char* _b = bb + (wr * 2 + ((FM) >> 1)) * 8192                \
                     + ((((FM) & 1) * 32) + r31) * 128;                \
    _Pragma("unroll") for (int ks = 0; ks < 4; ks++)                   \
      afr[ks] = *(const bf16x8*)(_b + kbyte[ks]); }while(0)
#define LOAD_B() do{                                                   \
    _Pragma("unroll") for (int fn = 0; fn < 2; fn++){                  \
      const char* _b = bb + 32768 + wc * 8192 + (fn * 32 + r31) * 128; \
      _Pragma("unroll") for (int ks = 0; ks < 4; ks++)                 \
        bfr[fn][ks] = *(const bf16x8*)(_b + kbyte[ks]); } }while(0)
#define MFMA_F(FM)                                                     \
    _Pragma("unroll") for (int fn = 0; fn < 2; fn++)                   \
      _Pragma("unroll") for (int ks = 0; ks < 4; ks++)                 \
        acc[FM][fn] = __builtin_amdgcn_mfma_f32_32x32x16_bf16(         \
            afr[ks], bfr[fn][ks], acc[FM][fn], 0, 0, 0);
#define PH_SYNC do{ __builtin_amdgcn_s_barrier();                      \
    asm volatile("s_waitcnt lgkmcnt(0)" ::: "memory");                 \
    __builtin_amdgcn_sched_barrier(0); }while(0)

  // prologue: stage K-tile 0 into buffer 0, drain, sync
  STAGE_A(0, 0); STAGE_B(0, 0);
  asm volatile("s_waitcnt vmcnt(0)" ::: "memory");
  __builtin_amdgcn_s_barrier();

  for (int kt = 0; kt < 12; kt++){
    const char* bb = smem + (kt & 1) * 65536;
    const int nb = (kt & 1) ^ 1;
    const bool st = kt < 11;
    const int ko = (kt + 1) * 64;
    // P0: A-frag row-block 0 + all B-frags; stage A of next tile
    LOAD_A(0); LOAD_B();
    if (st) STAGE_A(ko, nb);
    PH_SYNC;
    __builtin_amdgcn_s_setprio(1); MFMA_F(0); __builtin_amdgcn_s_setprio(0);
    __builtin_amdgcn_s_barrier();
    // P1: A row-block 1; stage B of next tile
    LOAD_A(1);
    if (st) STAGE_B(ko, nb);
    PH_SYNC;
    __builtin_amdgcn_s_setprio(1); MFMA_F(1); __builtin_amdgcn_s_setprio(0);
    __builtin_amdgcn_s_barrier();
    // P2: A row-block 2
    LOAD_A(2);
    PH_SYNC;
    __builtin_amdgcn_s_setprio(1); MFMA_F(2); __builtin_amdgcn_s_setprio(0);
    __builtin_amdgcn_s_barrier();
    // P3: A row-block 3; drain next tile's stage before buffer flip
    LOAD_A(3);
    PH_SYNC;
    __builtin_amdgcn_s_setprio(1); MFMA_F(3); __builtin_amdgcn_s_setprio(0);
    asm volatile("s_waitcnt vmcnt(0)" ::: "memory");
    __builtin_amdgcn_s_barrier();
  }
#undef STAGE_A
#undef STAGE_B
#undef LOAD_A
#undef LOAD_B
#undef MFMA_F
#undef PH_SYNC

  // epilogue: stage C (256 x 512B rows) in LDS with 32B-chunk XOR, 16B stores
  __syncthreads();
  const int colblk2 = is_r ? colblk - 3 : colblk;
  const float* bp = is_r ? br : bl;
  const int cb = colblk2 * 256;
  float bb2[2];
  bb2[0] = bp[cb + wc * 64 + r31];
  bb2[1] = bp[cb + wc * 64 + 32 + r31];
#pragma unroll
  for (int fm = 0; fm < 4; fm++){
#pragma unroll
    for (int fn = 0; fn < 2; fn++){
      int col = wc * 64 + fn * 32 + r31;
#pragma unroll
      for (int r = 0; r < 16; r++){
        int row = wr * 128 + fm * 32 + (r & 3) + 8 * (r >> 2) + 4 * kh;
        int byte = row * 512 + ((col * 2) ^ (((row >> 2) & 3) << 5));
        *(__hip_bfloat16*)(smem + byte) = __float2bfloat16(acc[fm][fn][r] + bb2[fn]);
      }
    }
  }
  __syncthreads();
  __hip_bfloat16* C = is_r ? Cr : Cl;
#pragma unroll
  for (int p = 0; p < 16; p++){
    int ba = p * 8192 + t16;
    int lr = ba >> 9, inner = ba & 511;
    uint4 v = *(const uint4*)(smem + lr * 512 + (inner ^ (((lr >> 2) & 3) << 5)));
    *(uint4*)(C + (size_t)(row0 + lr) * H + cb + (inner >> 1)) = v;
  }
}

// ---------------- 128x128 4-wave GEMM with row-compaction (layer 2, validated) ----------------
__global__ __launch_bounds__(256, 3) void gemm_fused_kernel(
    const __hip_bfloat16* __restrict__ A,
    const __hip_bfloat16* __restrict__ WT,
    const float* __restrict__ bl, const float* __restrict__ br,
    __hip_bfloat16* __restrict__ Cl, __hip_bfloat16* __restrict__ Cr,
    const int* __restrict__ rmap, const int* __restrict__ nr_p,
    int panels, int Mr){
  __shared__ char smem[49152];          // 3 x (As 8KB | Bs 8KB)

  int wgid = blockIdx.x;
  int panel = wgid / 12, colblk = wgid % 12;   // identity: spreads active blocks
  int row0 = panel * BM;
  const bool is_r = colblk >= 6;
  int nrl = *nr_p;
  if (is_r){ if (row0 >= Mr) return; }
  else     { if (row0 >= nrl) return; }
  const bool remap = !is_r;

  const int t = threadIdx.x;
  const int sr = t >> 2;
  const int scs = (((t & 3) ^ ((sr >> 1) & 3)) * 8);
  const int t16 = t * 16;
  int ra0 = row0 + sr, ra1 = row0 + sr + 64;
  if (remap){
    ra0 = rmap[min(ra0, nrl - 1)];
    ra1 = rmap[min(ra1, nrl - 1)];
  }
  const __hip_bfloat16* pa0 = A + (size_t)ra0 * H + scs;
  const __hip_bfloat16* pa1 = A + (size_t)ra1 * H + scs;
  const __hip_bfloat16* pb0 = WT + (size_t)(colblk * 128 + sr) * H + scs;
  const __hip_bfloat16* pb1 = pb0 + (size_t)64 * H;

  const int l = t & 63, w = t >> 6;
  const int wm = (w >> 1) * 64, wn = (w & 1) * 64;
  const int r0 = l & 15;
  const int kcs2 = (((l >> 4) ^ ((r0 >> 1) & 3)) * 16);

  f32x4 acc[4][4];
#pragma unroll
  for (int m = 0; m < 4; m++)
#pragma unroll
    for (int n = 0; n < 4; n++) acc[m][n] = (f32x4){0.f, 0.f, 0.f, 0.f};

#define STAGE(kt, b) do{                                   \
    int _k0 = (kt) * 32;                                   \
    char* _bs = smem + (b) * 16384;                        \
    gload16(pa0 + _k0, _bs + t16);                         \
    gload16(pa1 + _k0, _bs + 4096 + t16);                  \
    gload16(pb0 + _k0, _bs + 8192 + t16);                  \
    gload16(pb1 + _k0, _bs + 12288 + t16);                 \
  }while(0)

  STAGE(0, 0);
  STAGE(1, 1);

  for (int kt = 0; kt < 24; kt++){
    if (kt < 23) asm volatile("s_waitcnt vmcnt(4)" ::: "memory");
    else         asm volatile("s_waitcnt vmcnt(0)" ::: "memory");
    __builtin_amdgcn_s_barrier();
    __builtin_amdgcn_sched_barrier(0);
    if (kt + 2 < 24) STAGE(kt + 2, (kt + 2) % 3);
    const char* base = smem + (kt % 3) * 16384;
    bf16x8 af[4], bfr[4];
#pragma unroll
    for (int m = 0; m < 4; m++)
      af[m]  = *(const bf16x8*)(base + (wm + m * 16 + r0) * 64 + kcs2);
#pragma unroll
    for (int n = 0; n < 4; n++)
      bfr[n] = *(const bf16x8*)(base + 8192 + (wn + n * 16 + r0) * 64 + kcs2);
#pragma unroll
    for (int m = 0; m < 4; m++)
#pragma unroll
      for (int n = 0; n < 4; n++)
        acc[m][n] = __builtin_amdgcn_mfma_f32_16x16x32_bf16(af[m], bfr[n], acc[m][n], 0, 0, 0);
  }
#undef STAGE

  __syncthreads();
  const int rgrp = (l >> 4) * 4;
  const float* bp = is_r ? br : bl;
  const int cb = (is_r ? colblk - 6 : colblk) * 128;
#pragma unroll
  for (int n = 0; n < 4; n++){
    int lc = wn + n * 16 + r0;
    float bb = bp[cb + lc];
#pragma unroll
    for (int m = 0; m < 4; m++){
#pragma unroll
      for (int jj = 0; jj < 4; jj++){
        int lr = wm + m * 16 + rgrp + jj;
        int byte = lr * 256 + ((lc * 2) ^ (((lr >> 2) & 3) << 5));
        *(__hip_bfloat16*)(smem + byte) = __float2bfloat16(acc[m][n][jj] + bb);
      }
    }
  }
  __syncthreads();
  __hip_bfloat16* C = is_r ? Cr : Cl;
#pragma unroll
  for (int p = 0; p < 8; p++){
    int ba = p * 4096 + t16;
    int lr = ba >> 8, inner = ba & 255;
    int gr = row0 + lr;
    if (!is_r && gr >= nrl) continue;
    int orow = remap ? rmap[gr] : gr;
    uint4 v = *(const uint4*)(smem + lr * 256 + (inner ^ (((lr >> 2) & 3) << 5)));
    *(uint4*)(C + (size_t)orow * H + cb + (inner >> 1)) = v;
  }
}

// ---------------- edge helpers ----------------
__device__ __forceinline__ int e_src(const int* ep, int E0, int k){
  return (k < E0) ? ep[k] : (k - E0);
}
__device__ __forceinline__ int e_dst(const int* ep, int E0, int k){
  return (k < E0) ? ep[E0 + k] : (k - E0);
}

// ---------------- CSR build + layer-2 src marking (fused) ----------------
__global__ __launch_bounds__(256) void count_mark_kernel(const int* __restrict__ ep,
                                                         int E0, int E, int L,
                                                         int* __restrict__ cnt,
                                                         int* __restrict__ flag){
  int k = blockIdx.x * 256 + threadIdx.x;
  if (k >= E) return;
  int d = e_dst(ep, E0, k);
  atomicAdd(&cnt[d], 1);
  if (d < L) flag[e_src(ep, E0, k)] = 1;       // benign same-value race
}

// dual chunk-scan: q=0 scans cnt->off/sums, q=1 scans flag->fpos/fsums
__global__ __launch_bounds__(1024) void scan1_dual_kernel(
    const int* __restrict__ a0, int* __restrict__ o0, int* __restrict__ s0,
    const int* __restrict__ a1, int* __restrict__ o1, int* __restrict__ s1, int n){
  __shared__ int lds[1024];
  const int* as[2] = {a0, a1};
  int* os[2] = {o0, o1};
  int* ss[2] = {s0, s1};
  int tid = threadIdx.x;
  int gi = blockIdx.x * 1024 + tid;
  for (int q = 0; q < 2; q++){
    __syncthreads();
    int v = (gi < n) ? as[q][gi] : 0;
    lds[tid] = v;
    __syncthreads();
    for (int o = 1; o < 1024; o <<= 1){
      int tv = (tid >= o) ? lds[tid - o] : 0;
      __syncthreads();
      lds[tid] += tv;
      __syncthreads();
    }
    if (gi < n) os[q][gi] = lds[tid] - v;
    if (tid == 1023) ss[q][blockIdx.x] = lds[1023];
  }
}

__global__ void scan2_dual_kernel(int* __restrict__ s0, int* __restrict__ o0,
                                  int* __restrict__ s1, int* __restrict__ o1,
                                  int nb, int n){
  int lane = threadIdx.x;                      // single wave of 64, nb <= 64
  int* ss[2] = {s0, s1};
  int* os[2] = {o0, o1};
  for (int q = 0; q < 2; q++){
    int v = (lane < nb) ? ss[q][lane] : 0;
    int incl = v;
#pragma unroll
    for (int o = 1; o < 64; o <<= 1){
      int t = __shfl_up(incl, o);
      if (lane >= o) incl += t;
    }
    if (lane < nb) ss[q][lane] = incl - v;
    if (lane == nb - 1) os[q][n] = incl;
  }
}

// apply block offsets to off/cur and fpos; emit ordered compaction list
__global__ __launch_bounds__(1024) void scan3f_kernel(
    int* __restrict__ off, int* __restrict__ cur, const int* __restrict__ sums,
    int* __restrict__ fpos, const int* __restrict__ fsums,
    const int* __restrict__ flag, int* __restrict__ list, int n){
  int gi = blockIdx.x * 1024 + threadIdx.x;
  if (gi < n){
    int v = off[gi] + sums[blockIdx.x];
    off[gi] = v;
    cur[gi] = v;
    int fp = fpos[gi] + fsums[blockIdx.x];
    fpos[gi] = fp;
    if (flag[gi]) list[fp] = gi;
  }
}

__global__ __launch_bounds__(256) void fill_kernel(const int* __restrict__ ep, int E0, int E,
                                                   int* __restrict__ cur, int* __restrict__ csr){
  int k = blockIdx.x * 256 + threadIdx.x;
  if (k >= E) return;
  int d = e_dst(ep, E0, k);
  int pos = atomicAdd(&cur[d], 1);
  csr[pos] = k;
}

// ---------------- fused GAT attend+aggregate+LN+GELU: one WAVE per dst ----------------
template<typename OutT>
__global__ __launch_bounds__(256) void agat_kernel(
    const __hip_bfloat16* __restrict__ xl, const __hip_bfloat16* __restrict__ xr,
    const float* __restrict__ att, const int* __restrict__ off,
    const int* __restrict__ csr, const int* __restrict__ ep, int E0,
    const float* __restrict__ bias, const float* __restrict__ g,
    const float* __restrict__ b, OutT* __restrict__ out, int ndst){
  int d = blockIdx.x * 4 + (threadIdx.x >> 6);
  if (d >= ndst) return;
  int lane = threadIdx.x & 63;
  float xrv[12], attv[12];
  const unsigned* pr = (const unsigned*)(xr + (size_t)d * H);
#pragma unroll
  for (int i = 0; i < 3; i++){
    uint2 vr = *(const uint2*)&pr[lane * 2 + i * 128];
    float4 av = *(const float4*)&att[(lane + i * 64) * 4];
    xrv[i*4+0] = bf2f(vr.x); xrv[i*4+1] = bf2f(vr.x >> 16);
    xrv[i*4+2] = bf2f(vr.y); xrv[i*4+3] = bf2f(vr.y >> 16);
    attv[i*4+0] = av.x; attv[i*4+1] = av.y; attv[i*4+2] = av.z; attv[i*4+3] = av.w;
  }
  float m = -INFINITY, den = 0.f, acc[12];
#pragma unroll
  for (int t = 0; t < 12; t++) acc[t] = 0.f;
  int j0 = off[d], j1 = off[d + 1];
  int sj = (j0 < j1) ? e_src(ep, E0, csr[j0]) : 0;   // src prefetch pipeline
  for (int j = j0; j < j1; j++){
    int s_ = sj;
    if (j + 1 < j1) sj = e_src(ep, E0, csr[j + 1]);
    const unsigned* pl = (const unsigned*)(xl + (size_t)s_ * H);
    float xv[12];
#pragma unroll
    for (int i = 0; i < 3; i++){
      uint2 vl = *(const uint2*)&pl[lane * 2 + i * 128];
      xv[i*4+0] = bf2f(vl.x); xv[i*4+1] = bf2f(vl.x >> 16);
      xv[i*4+2] = bf2f(vl.y); xv[i*4+3] = bf2f(vl.y >> 16);
    }
    float p = 0.f;
#pragma unroll
    for (int t = 0; t < 12; t++){
      float v = xv[t] + xrv[t];
      v = (v > 0.f) ? v : 0.2f * v;
      p += v * attv[t];
    }
    p = wave_sum(p);
    float mn = fmaxf(m, p);
    float sc = __expf(m - mn), wgt = __expf(p - mn);
    den = den * sc + wgt;
#pragma unroll
    for (int t = 0; t < 12; t++) acc[t] = acc[t] * sc + wgt * xv[t];
    m = mn;
  }
  float inv = 1.0f / den;
  float y[12];
  float s1 = 0.f;
#pragma unroll
  for (int i = 0; i < 3; i++){
    float4 bv = *(const float4*)&bias[(lane + i * 64) * 4];
    y[i*4+0] = acc[i*4+0] * inv + bv.x;
    y[i*4+1] = acc[i*4+1] * inv + bv.y;
    y[i*4+2] = acc[i*4+2] * inv + bv.z;
    y[i*4+3] = acc[i*4+3] * inv + bv.w;
  }
#pragma unroll
  for (int t = 0; t < 12; t++) s1 += y[t];
  float mean = wave_sum(s1) * (1.0f / H);
  float s2 = 0.f;
#pragma unroll
  for (int t = 0; t < 12; t++){ float dt = y[t] - mean; s2 += dt * dt; }
  float rstd = rsqrtf(wave_sum(s2) * (1.0f / H) + 1e-5f);
  OutT* op = out + (size_t)d * H;
#pragma unroll
  for (int i = 0; i < 3; i++){
    float4 gv = *(const float4*)&g[(lane + i * 64) * 4];
    float4 bv = *(const float4*)&b[(lane + i * 64) * 4];
    float z0 = gelu_exact((y[i*4+0] - mean) * rstd * gv.x + bv.x);
    float z1 = gelu_exact((y[i*4+1] - mean) * rstd * gv.y + bv.y);
    float z2 = gelu_exact((y[i*4+2] - mean) * rstd * gv.z + bv.z);
    float z3 = gelu_exact((y[i*4+3] - mean) * rstd * gv.w + bv.w);
    if constexpr (sizeof(OutT) == 2){
      uint2 pk; pk.x = f2bf2(z0, z1); pk.y = f2bf2(z2, z3);
      *(uint2*)((unsigned*)op + lane * 2 + i * 128) = pk;
    } else {
      float4 fv; fv.x = z0; fv.y = z1; fv.z = z2; fv.w = z3;
      *(float4*)&op[(lane + i * 64) * 4] = fv;
    }
  }
}

extern "C" void kernel_launch(void* const* d_in, const int* in_sizes, int n_in,
                              void* d_out, int out_size, void* d_ws, size_t ws_size,
                              hipStream_t stream){
  const float* emb   = (const float*)d_in[0];
  const float* feats = (const float*)d_in[1];
  const int*   edges = (const int*)d_in[2];
  const float* Wl2 = (const float*)d_in[4],  *bl2 = (const float*)d_in[5];
  const float* Wr2 = (const float*)d_in[6],  *br2 = (const float*)d_in[7];
  const float* att2= (const float*)d_in[8],  *bias2=(const float*)d_in[9];
  const float* Wl3 = (const float*)d_in[10], *bl3 = (const float*)d_in[11];
  const float* Wr3 = (const float*)d_in[12], *br3 = (const float*)d_in[13];
  const float* att3= (const float*)d_in[14], *bias3=(const float*)d_in[15];
  const float* g1 = (const float*)d_in[16], *b1 = (const float*)d_in[17];
  const float* g2 = (const float*)d_in[18], *b2 = (const float*)d_in[19];
  const float* g3 = (const float*)d_in[20], *b3 = (const float*)d_in[21];

  const int N  = in_sizes[1] / H;             // 50000
  const int E0 = in_sizes[2] / 2;             // 100000
  const int E  = E0 + N;                      // 150000
  const int L  = 4096;                        // labels_size
  const int panels256 = (N + 255) / 256;              // 196 (196*6 % 8 == 0)
  const int Mpad = panels256 * 256;                    // 50176
  const int panels128 = Mpad / BM;                     // 392
  const int nchunk = (N + 1023) / 1024;                // 49 (<= 64)

  __hip_bfloat16* ab  = (__hip_bfloat16*)d_ws;          // [Mpad][H] GEMM input
  __hip_bfloat16* xl  = ab + (size_t)Mpad * H;          // [Mpad][H]
  __hip_bfloat16* xr  = xl + (size_t)Mpad * H;          // [Mpad][H]
  __hip_bfloat16* wt2 = xr + (size_t)Mpad * H;          // [1536][H]
  __hip_bfloat16* wt3 = wt2 + (size_t)2 * H * H;        // [1536][H]
  int* cnt  = (int*)(wt3 + (size_t)2 * H * H);          // [N]
  int* flag = cnt + N;                                  // [N]
  int* off  = flag + N;                                 // [N+1]
  int* cur  = off + N + 1;                              // [N]
  int* csr  = cur + N;                                  // [E]
  int* sums = csr + E;                                  // [64]
  int* fpos = sums + 64;                                // [N+1]
  int* fsums= fpos + N + 1;                             // [64]
  int* list = fsums + 64;                               // [N]

  float* out_f = (float*)d_out;

  // output 0: passthrough copy of input_embeddings
  hipMemcpyAsync(out_f, emb, (size_t)in_sizes[0] * sizeof(float),
                 hipMemcpyDeviceToDevice, stream);

  // CSR by dst + layer-2 src flags (one edge pass, merged scans)
  hipMemsetAsync(cnt, 0, (size_t)2 * N * sizeof(int), stream);
  count_mark_kernel<<<(E + 255) / 256, 256, 0, stream>>>(edges, E0, E, L, cnt, flag);
  scan1_dual_kernel<<<nchunk, 1024, 0, stream>>>(cnt, off, sums, flag, fpos, fsums, N);
  scan2_dual_kernel<<<1, 64, 0, stream>>>(sums, off, fsums, fpos, nchunk, N);
  scan3f_kernel<<<nchunk, 1024, 0, stream>>>(off, cur, sums, fpos, fsums, flag, list, N);
  fill_kernel<<<(E + 255) / 256, 256, 0, stream>>>(edges, E0, E, cur, csr);

  // weights -> bf16 transposed, concatenated [Wl^T ; Wr^T] (one launch)
  dim3 wgrid(H / 32, H / 32, 4);
  wt_bf16_kernel<<<wgrid, 256, 0, stream>>>(Wl2, Wr2, Wl3, Wr3,
                                            wt2, wt2 + (size_t)H * H,
                                            wt3, wt3 + (size_t)H * H);

  // ---- layer 1 (full N): 256x256 8-wave 32x32-MFMA GEMM ----
  lnw_kernel<<<(N + 3) / 4, 256, 0, stream>>>(feats, g1, b1, ab, N);
  gemm256_kernel<<<panels256 * 6, 512, 0, stream>>>(ab, wt2, bl2, br2, xl, xr,
                                                    panels256, N);
  agat_kernel<__hip_bfloat16><<<(N + 3) / 4, 256, 0, stream>>>(
      xl, xr, att2, off, csr, edges, E0, bias2, g2, b2, ab, N);

  // ---- layer 2 (xl only for compacted src rows; xr + aggregation only rows < L) ----
  gemm_fused_kernel<<<panels128 * 12, 256, 0, stream>>>(ab, wt3, bl3, br3, xl, xr,
                                                        list, fpos + N, panels128, L);
  agat_kernel<float><<<(L + 3) / 4, 256, 0, stream>>>(
      xl, xr, att3, off, csr, edges, E0, bias3, g3, b3, out_f + in_sizes[0], L);
}

// Round 12
// 206.417 us; speedup vs baseline: 2.3910x; 1.8470x over previous
//
#include <hip/hip_runtime.h>
#include <hip/hip_bf16.h>
#include <math.h>

#define H 768
#define BM 128

typedef __attribute__((ext_vector_type(4))) float f32x4;
typedef __attribute__((ext_vector_type(8))) short bf16x8;

__device__ __forceinline__ float bf2f(unsigned u16v){
  return __uint_as_float((u16v & 0xffffu) << 16);
}
__device__ __forceinline__ unsigned f2bf2(float a, float b){
  __hip_bfloat16 ha = __float2bfloat16(a), hb = __float2bfloat16(b);
  return (unsigned)*(unsigned short*)&ha | ((unsigned)*(unsigned short*)&hb << 16);
}
__device__ __forceinline__ float gelu_exact(float x){
  return 0.5f * x * (1.0f + erff(x * 0.70710678118654752f));
}
__device__ __forceinline__ void gload16(const void* g, void* l){
  __builtin_amdgcn_global_load_lds(
      (const __attribute__((address_space(1))) unsigned int*)g,
      (__attribute__((address_space(3))) unsigned int*)l,
      16, 0, 0);
}
__device__ __forceinline__ float wave_sum(float p){
#pragma unroll
  for (int o = 32; o; o >>= 1) p += __shfl_xor(p, o);
  return p;
}

// ---------------- LayerNorm + exact GELU over a row LIST: one WAVE per row ----------------
__global__ __launch_bounds__(256) void lnw_list_kernel(
    const float* __restrict__ in, const float* __restrict__ g,
    const float* __restrict__ b, __hip_bfloat16* __restrict__ out,
    const int* __restrict__ rlist, const int* __restrict__ np){
  int i = blockIdx.x * 4 + (threadIdx.x >> 6);
  if (i >= *np) return;
  int row = rlist[i];
  int lane = threadIdx.x & 63;
  const float* rp = in + (size_t)row * H;
  float v[12];
#pragma unroll
  for (int q = 0; q < 3; q++){
    float4 t = *(const float4*)&rp[(lane + q * 64) * 4];
    v[q*4+0] = t.x; v[q*4+1] = t.y; v[q*4+2] = t.z; v[q*4+3] = t.w;
  }
  float s = 0.f;
#pragma unroll
  for (int t = 0; t < 12; t++) s += v[t];
  float mean = wave_sum(s) * (1.0f / H);
  float s2 = 0.f;
#pragma unroll
  for (int t = 0; t < 12; t++){ float d = v[t] - mean; s2 += d * d; }
  float rstd = rsqrtf(wave_sum(s2) * (1.0f / H) + 1e-5f);
  unsigned* op = (unsigned*)(out + (size_t)row * H);
#pragma unroll
  for (int q = 0; q < 3; q++){
    float4 gv = *(const float4*)&g[(lane + q * 64) * 4];
    float4 bv = *(const float4*)&b[(lane + q * 64) * 4];
    float z0 = gelu_exact((v[q*4+0] - mean) * rstd * gv.x + bv.x);
    float z1 = gelu_exact((v[q*4+1] - mean) * rstd * gv.y + bv.y);
    float z2 = gelu_exact((v[q*4+2] - mean) * rstd * gv.z + bv.z);
    float z3 = gelu_exact((v[q*4+3] - mean) * rstd * gv.w + bv.w);
    uint2 pk; pk.x = f2bf2(z0, z1); pk.y = f2bf2(z2, z3);
    *(uint2*)&op[lane * 2 + q * 128] = pk;
  }
}

// ---------------- weight transpose + f32->bf16 (all 4 matrices, z-indexed) ----------------
__global__ __launch_bounds__(256) void wt_bf16_kernel(
    const float* __restrict__ W0, const float* __restrict__ W1,
    const float* __restrict__ W2, const float* __restrict__ W3,
    __hip_bfloat16* __restrict__ T0, __hip_bfloat16* __restrict__ T1,
    __hip_bfloat16* __restrict__ T2, __hip_bfloat16* __restrict__ T3){
  int z = blockIdx.z;
  const float* W = (z == 0) ? W0 : (z == 1) ? W1 : (z == 2) ? W2 : W3;
  __hip_bfloat16* WT = (z == 0) ? T0 : (z == 1) ? T1 : (z == 2) ? T2 : T3;
  __shared__ float tile[32][33];
  int k0 = blockIdx.x * 32, n0 = blockIdx.y * 32;
  int tx = threadIdx.x & 31, ty = threadIdx.x >> 5;   // 32 x 8
#pragma unroll
  for (int i = 0; i < 32; i += 8)
    tile[ty + i][tx] = W[(size_t)(k0 + ty + i) * H + n0 + tx];
  __syncthreads();
#pragma unroll
  for (int i = 0; i < 32; i += 8)
    WT[(size_t)(n0 + ty + i) * H + k0 + tx] = __float2bfloat16(tile[tx][ty + i]);
}

// ---------------- 128x128 4-wave GEMM, dual row-compaction (both layers) ----------------
// [Cl | Cr] = A[...] @ WT[1536,768]^T (+bias). Validated round-4..11 sync
// structure (3-buffer, depth-2, counted vmcnt). xl blocks gather/store rows via
// rmapL (count *nrLp); xr blocks via rmapR (count *nrRp) or identity < MrR.
__global__ __launch_bounds__(256, 3) void gemm_fused_kernel(
    const __hip_bfloat16* __restrict__ A,
    const __hip_bfloat16* __restrict__ WT,
    const float* __restrict__ bl, const float* __restrict__ br,
    __hip_bfloat16* __restrict__ Cl, __hip_bfloat16* __restrict__ Cr,
    const int* __restrict__ rmapL, const int* __restrict__ nrLp,
    const int* __restrict__ rmapR, const int* __restrict__ nrRp, int MrR){
  __shared__ char smem[49152];          // 3 x (As 8KB | Bs 8KB)

  int wgid = blockIdx.x;
  int panel = wgid / 12, colblk = wgid % 12;   // identity: spreads active blocks
  int row0 = panel * BM;
  const bool is_r = colblk >= 6;
  const int* rmap = is_r ? rmapR : rmapL;
  int nr = is_r ? (rmapR ? *nrRp : MrR) : *nrLp;
  if (row0 >= nr) return;
  const bool remap = (rmap != nullptr);

  const int t = threadIdx.x;
  const int sr = t >> 2;
  const int scs = (((t & 3) ^ ((sr >> 1) & 3)) * 8);
  const int t16 = t * 16;
  int ra0 = min(row0 + sr, nr - 1), ra1 = min(row0 + sr + 64, nr - 1);
  if (remap){ ra0 = rmap[ra0]; ra1 = rmap[ra1]; }
  const __hip_bfloat16* pa0 = A + (size_t)ra0 * H + scs;
  const __hip_bfloat16* pa1 = A + (size_t)ra1 * H + scs;
  const __hip_bfloat16* pb0 = WT + (size_t)(colblk * 128 + sr) * H + scs;
  const __hip_bfloat16* pb1 = pb0 + (size_t)64 * H;

  const int l = t & 63, w = t >> 6;
  const int wm = (w >> 1) * 64, wn = (w & 1) * 64;
  const int r0 = l & 15;
  const int kcs2 = (((l >> 4) ^ ((r0 >> 1) & 3)) * 16);

  f32x4 acc[4][4];
#pragma unroll
  for (int m = 0; m < 4; m++)
#pragma unroll
    for (int n = 0; n < 4; n++) acc[m][n] = (f32x4){0.f, 0.f, 0.f, 0.f};

#define STAGE(kt, b) do{                                   \
    int _k0 = (kt) * 32;                                   \
    char* _bs = smem + (b) * 16384;                        \
    gload16(pa0 + _k0, _bs + t16);                         \
    gload16(pa1 + _k0, _bs + 4096 + t16);                  \
    gload16(pb0 + _k0, _bs + 8192 + t16);                  \
    gload16(pb1 + _k0, _bs + 12288 + t16);                 \
  }while(0)

  STAGE(0, 0);
  STAGE(1, 1);

  for (int kt = 0; kt < 24; kt++){
    if (kt < 23) asm volatile("s_waitcnt vmcnt(4)" ::: "memory");
    else         asm volatile("s_waitcnt vmcnt(0)" ::: "memory");
    __builtin_amdgcn_s_barrier();
    __builtin_amdgcn_sched_barrier(0);
    if (kt + 2 < 24) STAGE(kt + 2, (kt + 2) % 3);
    const char* base = smem + (kt % 3) * 16384;
    bf16x8 af[4], bfr[4];
#pragma unroll
    for (int m = 0; m < 4; m++)
      af[m]  = *(const bf16x8*)(base + (wm + m * 16 + r0) * 64 + kcs2);
#pragma unroll
    for (int n = 0; n < 4; n++)
      bfr[n] = *(const bf16x8*)(base + 8192 + (wn + n * 16 + r0) * 64 + kcs2);
#pragma unroll
    for (int m = 0; m < 4; m++)
#pragma unroll
      for (int n = 0; n < 4; n++)
        acc[m][n] = __builtin_amdgcn_mfma_f32_16x16x32_bf16(af[m], bfr[n], acc[m][n], 0, 0, 0);
  }
#undef STAGE

  __syncthreads();
  const int rgrp = (l >> 4) * 4;
  const float* bp = is_r ? br : bl;
  const int cb = (is_r ? colblk - 6 : colblk) * 128;
#pragma unroll
  for (int n = 0; n < 4; n++){
    int lc = wn + n * 16 + r0;
    float bb = bp[cb + lc];
#pragma unroll
    for (int m = 0; m < 4; m++){
#pragma unroll
      for (int jj = 0; jj < 4; jj++){
        int lr = wm + m * 16 + rgrp + jj;
        int byte = lr * 256 + ((lc * 2) ^ (((lr >> 2) & 3) << 5));
        *(__hip_bfloat16*)(smem + byte) = __float2bfloat16(acc[m][n][jj] + bb);
      }
    }
  }
  __syncthreads();
  __hip_bfloat16* C = is_r ? Cr : Cl;
#pragma unroll
  for (int p = 0; p < 8; p++){
    int ba = p * 4096 + t16;
    int lr = ba >> 8, inner = ba & 255;
    int gr = row0 + lr;
    if (gr >= nr) continue;
    int orow = remap ? rmap[gr] : gr;
    uint4 v = *(const uint4*)(smem + lr * 256 + (inner ^ (((lr >> 2) & 3) << 5)));
    *(uint4*)(C + (size_t)orow * H + cb + (inner >> 1)) = v;
  }
}

// ---------------- edge helpers ----------------
__device__ __forceinline__ int e_src(const int* ep, int E0, int k){
  return (k < E0) ? ep[k] : (k - E0);
}
__device__ __forceinline__ int e_dst(const int* ep, int E0, int k){
  return (k < E0) ? ep[E0 + k] : (k - E0);
}

// ---------------- CSR build + S3 marking (dst<L srcs) ----------------
__global__ __launch_bounds__(256) void count_mark_kernel(const int* __restrict__ ep,
                                                         int E0, int E, int L,
                                                         int* __restrict__ cnt,
                                                         int* __restrict__ flag){
  int k = blockIdx.x * 256 + threadIdx.x;
  if (k >= E) return;
  int d = e_dst(ep, E0, k);
  atomicAdd(&cnt[d], 1);
  if (d < L) flag[e_src(ep, E0, k)] = 1;       // S3; benign same-value race
}

// S2 marking: srcs of edges whose dst is in S3 (requires flag complete)
__global__ __launch_bounds__(256) void mark2_kernel(const int* __restrict__ ep,
                                                    int E0, int E,
                                                    const int* __restrict__ flag,
                                                    int* __restrict__ flag2){
  int k = blockIdx.x * 256 + threadIdx.x;
  if (k >= E) return;
  if (flag[e_dst(ep, E0, k)]) flag2[e_src(ep, E0, k)] = 1;
}

// tri chunk-scan: q0 cnt->off/sums, q1 flag->fpos/fsums, q2 flag2->fpos2/fsums2
__global__ __launch_bounds__(1024) void scan1_tri_kernel(
    const int* __restrict__ a0, int* __restrict__ o0, int* __restrict__ s0,
    const int* __restrict__ a1, int* __restrict__ o1, int* __restrict__ s1,
    const int* __restrict__ a2, int* __restrict__ o2, int* __restrict__ s2, int n){
  __shared__ int lds[1024];
  const int* as[3] = {a0, a1, a2};
  int* os[3] = {o0, o1, o2};
  int* ss[3] = {s0, s1, s2};
  int tid = threadIdx.x;
  int gi = blockIdx.x * 1024 + tid;
  for (int q = 0; q < 3; q++){
    __syncthreads();
    int v = (gi < n) ? as[q][gi] : 0;
    lds[tid] = v;
    __syncthreads();
    for (int o = 1; o < 1024; o <<= 1){
      int tv = (tid >= o) ? lds[tid - o] : 0;
      __syncthreads();
      lds[tid] += tv;
      __syncthreads();
    }
    if (gi < n) os[q][gi] = lds[tid] - v;
    if (tid == 1023) ss[q][blockIdx.x] = lds[1023];
  }
}

__global__ void scan2_tri_kernel(int* __restrict__ s0, int* __restrict__ o0,
                                 int* __restrict__ s1, int* __restrict__ o1,
                                 int* __restrict__ s2, int* __restrict__ o2,
                                 int nb, int n){
  int lane = threadIdx.x;                      // single wave of 64, nb <= 64
  int* ss[3] = {s0, s1, s2};
  int* os[3] = {o0, o1, o2};
  for (int q = 0; q < 3; q++){
    int v = (lane < nb) ? ss[q][lane] : 0;
    int incl = v;
#pragma unroll
    for (int o = 1; o < 64; o <<= 1){
      int t = __shfl_up(incl, o);
      if (lane >= o) incl += t;
    }
    if (lane < nb) ss[q][lane] = incl - v;
    if (lane == nb - 1) os[q][n] = incl;
  }
}

// apply block offsets; emit cur copy and both ordered compaction lists
__global__ __launch_bounds__(1024) void scan3_tri_kernel(
    int* __restrict__ off, int* __restrict__ cur, const int* __restrict__ sums,
    int* __restrict__ fpos, const int* __restrict__ fsums,
    const int* __restrict__ flag, int* __restrict__ list,
    int* __restrict__ fpos2, const int* __restrict__ fsums2,
    const int* __restrict__ flag2, int* __restrict__ list2, int n){
  int gi = blockIdx.x * 1024 + threadIdx.x;
  if (gi < n){
    int v = off[gi] + sums[blockIdx.x];
    off[gi] = v;
    cur[gi] = v;
    int fp = fpos[gi] + fsums[blockIdx.x];
    fpos[gi] = fp;
    if (flag[gi]) list[fp] = gi;
    int fp2 = fpos2[gi] + fsums2[blockIdx.x];
    fpos2[gi] = fp2;
    if (flag2[gi]) list2[fp2] = gi;
  }
}

__global__ __launch_bounds__(256) void fill_kernel(const int* __restrict__ ep, int E0, int E,
                                                   int* __restrict__ cur, int* __restrict__ csr){
  int k = blockIdx.x * 256 + threadIdx.x;
  if (k >= E) return;
  int d = e_dst(ep, E0, k);
  int pos = atomicAdd(&cur[d], 1);
  csr[pos] = k;
}

// ---------------- fused GAT attend+aggregate+LN+GELU: one WAVE per dst ----------------
// dlist != null: wave i handles dst = dlist[i], i < *ndp. Else dst = i < ndst.
template<typename OutT>
__global__ __launch_bounds__(256) void agat_kernel(
    const __hip_bfloat16* __restrict__ xl, const __hip_bfloat16* __restrict__ xr,
    const float* __restrict__ att, const int* __restrict__ off,
    const int* __restrict__ csr, const int* __restrict__ ep, int E0,
    const float* __restrict__ bias, const float* __restrict__ g,
    const float* __restrict__ b, OutT* __restrict__ out,
    const int* __restrict__ dlist, const int* __restrict__ ndp, int ndst){
  int i = blockIdx.x * 4 + (threadIdx.x >> 6);
  int lim = dlist ? *ndp : ndst;
  if (i >= lim) return;
  int d = dlist ? dlist[i] : i;
  int lane = threadIdx.x & 63;
  float xrv[12], attv[12];
  const unsigned* pr = (const unsigned*)(xr + (size_t)d * H);
#pragma unroll
  for (int q = 0; q < 3; q++){
    uint2 vr = *(const uint2*)&pr[lane * 2 + q * 128];
    float4 av = *(const float4*)&att[(lane + q * 64) * 4];
    xrv[q*4+0] = bf2f(vr.x); xrv[q*4+1] = bf2f(vr.x >> 16);
    xrv[q*4+2] = bf2f(vr.y); xrv[q*4+3] = bf2f(vr.y >> 16);
    attv[q*4+0] = av.x; attv[q*4+1] = av.y; attv[q*4+2] = av.z; attv[q*4+3] = av.w;
  }
  float m = -INFINITY, den = 0.f, acc[12];
#pragma unroll
  for (int t = 0; t < 12; t++) acc[t] = 0.f;
  int j0 = off[d], j1 = off[d + 1];
  int sj = (j0 < j1) ? e_src(ep, E0, csr[j0]) : 0;   // src prefetch pipeline
  for (int j = j0; j < j1; j++){
    int s_ = sj;
    if (j + 1 < j1) sj = e_src(ep, E0, csr[j + 1]);
    const unsigned* pl = (const unsigned*)(xl + (size_t)s_ * H);
    float xv[12];
#pragma unroll
    for (int q = 0; q < 3; q++){
      uint2 vl = *(const uint2*)&pl[lane * 2 + q * 128];
      xv[q*4+0] = bf2f(vl.x); xv[q*4+1] = bf2f(vl.x >> 16);
      xv[q*4+2] = bf2f(vl.y); xv[q*4+3] = bf2f(vl.y >> 16);
    }
    float p = 0.f;
#pragma unroll
    for (int t = 0; t < 12; t++){
      float v = xv[t] + xrv[t];
      v = (v > 0.f) ? v : 0.2f * v;
      p += v * attv[t];
    }
    p = wave_sum(p);
    float mn = fmaxf(m, p);
    float sc = __expf(m - mn), wgt = __expf(p - mn);
    den = den * sc + wgt;
#pragma unroll
    for (int t = 0; t < 12; t++) acc[t] = acc[t] * sc + wgt * xv[t];
    m = mn;
  }
  float inv = 1.0f / den;
  float y[12];
  float s1 = 0.f;
#pragma unroll
  for (int q = 0; q < 3; q++){
    float4 bv = *(const float4*)&bias[(lane + q * 64) * 4];
    y[q*4+0] = acc[q*4+0] * inv + bv.x;
    y[q*4+1] = acc[q*4+1] * inv + bv.y;
    y[q*4+2] = acc[q*4+2] * inv + bv.z;
    y[q*4+3] = acc[q*4+3] * inv + bv.w;
  }
#pragma unroll
  for (int t = 0; t < 12; t++) s1 += y[t];
  float mean = wave_sum(s1) * (1.0f / H);
  float s2 = 0.f;
#pragma unroll
  for (int t = 0; t < 12; t++){ float dt = y[t] - mean; s2 += dt * dt; }
  float rstd = rsqrtf(wave_sum(s2) * (1.0f / H) + 1e-5f);
  OutT* op = out + (size_t)d * H;
#pragma unroll
  for (int q = 0; q < 3; q++){
    float4 gv = *(const float4*)&g[(lane + q * 64) * 4];
    float4 bv = *(const float4*)&b[(lane + q * 64) * 4];
    float z0 = gelu_exact((y[q*4+0] - mean) * rstd * gv.x + bv.x);
    float z1 = gelu_exact((y[q*4+1] - mean) * rstd * gv.y + bv.y);
    float z2 = gelu_exact((y[q*4+2] - mean) * rstd * gv.z + bv.z);
    float z3 = gelu_exact((y[q*4+3] - mean) * rstd * gv.w + bv.w);
    if constexpr (sizeof(OutT) == 2){
      uint2 pk; pk.x = f2bf2(z0, z1); pk.y = f2bf2(z2, z3);
      *(uint2*)((unsigned*)op + lane * 2 + q * 128) = pk;
    } else {
      float4 fv; fv.x = z0; fv.y = z1; fv.z = z2; fv.w = z3;
      *(float4*)&op[(lane + q * 64) * 4] = fv;
    }
  }
}

extern "C" void kernel_launch(void* const* d_in, const int* in_sizes, int n_in,
                              void* d_out, int out_size, void* d_ws, size_t ws_size,
                              hipStream_t stream){
  const float* emb   = (const float*)d_in[0];
  const float* feats = (const float*)d_in[1];
  const int*   edges = (const int*)d_in[2];
  const float* Wl2 = (const float*)d_in[4],  *bl2 = (const float*)d_in[5];
  const float* Wr2 = (const float*)d_in[6],  *br2 = (const float*)d_in[7];
  const float* att2= (const float*)d_in[8],  *bias2=(const float*)d_in[9];
  const float* Wl3 = (const float*)d_in[10], *bl3 = (const float*)d_in[11];
  const float* Wr3 = (const float*)d_in[12], *br3 = (const float*)d_in[13];
  const float* att3= (const float*)d_in[14], *bias3=(const float*)d_in[15];
  const float* g1 = (const float*)d_in[16], *b1 = (const float*)d_in[17];
  const float* g2 = (const float*)d_in[18], *b2 = (const float*)d_in[19];
  const float* g3 = (const float*)d_in[20], *b3 = (const float*)d_in[21];

  const int N  = in_sizes[1] / H;             // 50000
  const int E0 = in_sizes[2] / 2;             // 100000
  const int E  = E0 + N;                      // 150000
  const int L  = 4096;                        // labels_size
  const int Mpad = ((N + 127) / 128) * 128;            // 50048 rows capacity
  const int panels128 = Mpad / BM;                     // 391
  const int nchunk = (N + 1023) / 1024;                // 49 (<= 64)

  __hip_bfloat16* ab  = (__hip_bfloat16*)d_ws;          // [Mpad][H] GEMM input
  __hip_bfloat16* xl  = ab + (size_t)Mpad * H;          // [Mpad][H]
  __hip_bfloat16* xr  = xl + (size_t)Mpad * H;          // [Mpad][H]
  __hip_bfloat16* wt2 = xr + (size_t)Mpad * H;          // [1536][H]
  __hip_bfloat16* wt3 = wt2 + (size_t)2 * H * H;        // [1536][H]
  int* cnt   = (int*)(wt3 + (size_t)2 * H * H);         // [N]   (zeroed together:)
  int* flag  = cnt + N;                                 // [N]   S3 flags
  int* flag2 = flag + N;                                // [N]   S2 flags
  int* off   = flag2 + N;                               // [N+1]
  int* cur   = off + N + 1;                             // [N]
  int* csr   = cur + N;                                 // [E]
  int* sums  = csr + E;                                 // [64]
  int* fpos  = sums + 64;                               // [N+1] S3 scan (+count)
  int* fsums = fpos + N + 1;                            // [64]
  int* fpos2 = fsums + 64;                              // [N+1] S2 scan (+count)
  int* fsums2= fpos2 + N + 1;                           // [64]
  int* list  = fsums2 + 64;                             // [N]   S3 row list
  int* list2 = list + N;                                // [N]   S2 row list

  float* out_f = (float*)d_out;

  // output 0: passthrough copy of input_embeddings
  hipMemcpyAsync(out_f, emb, (size_t)in_sizes[0] * sizeof(float),
                 hipMemcpyDeviceToDevice, stream);

  // CSR by dst + backward-slice row sets S3 (layer-2 srcs) and S2 (layer-1 srcs)
  hipMemsetAsync(cnt, 0, (size_t)3 * N * sizeof(int), stream);
  count_mark_kernel<<<(E + 255) / 256, 256, 0, stream>>>(edges, E0, E, L, cnt, flag);
  mark2_kernel<<<(E + 255) / 256, 256, 0, stream>>>(edges, E0, E, flag, flag2);
  scan1_tri_kernel<<<nchunk, 1024, 0, stream>>>(cnt, off, sums, flag, fpos, fsums,
                                                flag2, fpos2, fsums2, N);
  scan2_tri_kernel<<<1, 64, 0, stream>>>(sums, off, fsums, fpos, fsums2, fpos2, nchunk, N);
  scan3_tri_kernel<<<nchunk, 1024, 0, stream>>>(off, cur, sums, fpos, fsums, flag, list,
                                                fpos2, fsums2, flag2, list2, N);
  fill_kernel<<<(E + 255) / 256, 256, 0, stream>>>(edges, E0, E, cur, csr);

  // weights -> bf16 transposed, concatenated [Wl^T ; Wr^T] (one launch)
  dim3 wgrid(H / 32, H / 32, 4);
  wt_bf16_kernel<<<wgrid, 256, 0, stream>>>(Wl2, Wr2, Wl3, Wr3,
                                            wt2, wt2 + (size_t)H * H,
                                            wt3, wt3 + (size_t)H * H);

  const int* nS3 = fpos + N;    // |S3|
  const int* nS2 = fpos2 + N;   // |S2|

  // ---- layer 1 (sliced): LN over S2; xl over S2, xr over S3; aggregate dst in S3 ----
  lnw_list_kernel<<<(N + 3) / 4, 256, 0, stream>>>(feats, g1, b1, ab, list2, nS2);
  gemm_fused_kernel<<<panels128 * 12, 256, 0, stream>>>(ab, wt2, bl2, br2, xl, xr,
                                                        list2, nS2, list, nS3, 0);
  agat_kernel<__hip_bfloat16><<<(N + 3) / 4, 256, 0, stream>>>(
      xl, xr, att2, off, csr, edges, E0, bias2, g2, b2, ab, list, nS3, 0);

  // ---- layer 2: xl over S3; xr identity rows < L; aggregate dst < L ----
  gemm_fused_kernel<<<panels128 * 12, 256, 0, stream>>>(ab, wt3, bl3, br3, xl, xr,
                                                        list, nS3, nullptr, nullptr, L);
  agat_kernel<float><<<(L + 3) / 4, 256, 0, stream>>>(
      xl, xr, att3, off, csr, edges, E0, bias3, g3, b3, out_f + in_sizes[0],
      nullptr, nullptr, L);
}